// Round 1
// baseline (26223.651 us; speedup 1.0000x reference)
//
#include <hip/hip_runtime.h>
#include <math.h>

#define NNODES 30000
#define NEDGES 480000
#define NC 32
#define NL 3
#define NH 64
#define NBASIS 8
#define NSPEC 5
#define NOUT 160          // 5 paths * 32 channels
#define INV_AVG 0.0625f   // 1 / AVG_NEIGH

__device__ __forceinline__ float silu_f(float x) {
    return x / (1.f + __expf(-x));
}

// ---------------------------------------------------------------- geometry
__global__ void geom_kernel(const float* __restrict__ vec,
                            float* __restrict__ nhat,
                            float* __restrict__ rb) {
    int e = blockIdx.x * blockDim.x + threadIdx.x;
    if (e >= NEDGES) return;
    float vx = vec[3*e+0] * 0.25f;   // vectors / R_MAX
    float vy = vec[3*e+1] * 0.25f;
    float vz = vec[3*e+2] * 0.25f;
    float len = sqrtf(vx*vx + vy*vy + vz*vz);      // scaled length
    float inv = 1.f / fmaxf(len, 1e-9f);
    nhat[3*e+0] = vx * inv;
    nhat[3*e+1] = vy * inv;
    nhat[3*e+2] = vz * inv;
    float x = len * 0.25f;                         // lengths / R_MAX (again)
    float x3 = x*x*x;
    float x6 = x3*x3;
    float x7 = x6*x;
    float x8 = x7*x;
    float env = (x < 1.f) ? (1.f - 28.f*x6 + 48.f*x7 - 21.f*x8) : 0.f;
    float scale = 0.7071067811865476f * inv * env; // sqrt(2/R_MAX) / max(len,eps) * env
    #pragma unroll
    for (int i = 0; i < NBASIS; ++i) {
        rb[NBASIS*e + i] = scale * sinf((float)(i+1) * 3.14159265358979f * x);
    }
}

// ---------------------------------------------------------------- node init
__global__ void init_kernel(const int* __restrict__ specie,
                            const float* __restrict__ emb,
                            float* __restrict__ s) {
    int t = blockIdx.x * blockDim.x + threadIdx.x;
    if (t >= NNODES * NC) return;
    int n = t >> 5;
    int c = t & 31;
    s[t] = emb[specie[n] * NC + c];
}

// ---------------------------------------------------------------- edge pass
// thread-per-edge; radial weights in LDS (transposed for contiguous dot reads)
__global__ __launch_bounds__(256) void edge_kernel(
    const float* __restrict__ rb, const float* __restrict__ nhat,
    const int* __restrict__ senders, const int* __restrict__ receivers,
    const float* __restrict__ s_in, const float* __restrict__ v_in,
    const float* __restrict__ w1,   // [8][64]
    const float* __restrict__ w2,   // [64][64]
    const float* __restrict__ w3,   // [64][160]
    float* __restrict__ agg_s,      // [N][64]
    float* __restrict__ agg_v)      // [N][96][3]
{
    __shared__ float sW1[NBASIS * NH];   // transposed: [k][b]
    __shared__ float sW2[NH * NH];       // as-is:      [k][j]
    __shared__ float sW3[NOUT * NH];     // transposed: [j][k]

    for (int i = threadIdx.x; i < NBASIS * NH; i += 256) {
        int k = i >> 3, b = i & 7;
        sW1[i] = w1[b * NH + k];
    }
    for (int i = threadIdx.x; i < NH * NH; i += 256) sW2[i] = w2[i];
    for (int i = threadIdx.x; i < NOUT * NH; i += 256) {
        int j = i >> 6, k = i & 63;
        sW3[i] = w3[k * NOUT + j];
    }
    __syncthreads();

    int e = blockIdx.x * 256 + threadIdx.x;
    if (e >= NEDGES) return;

    float rbv[NBASIS];
    #pragma unroll
    for (int b = 0; b < NBASIS; ++b) rbv[b] = rb[e * NBASIS + b];

    // h2 accumulators; h1[k] recomputed on the fly inside the dynamic k-loop
    float acc[NH];
    #pragma unroll
    for (int j = 0; j < NH; ++j) acc[j] = 0.f;

    #pragma unroll 1
    for (int k = 0; k < NH; ++k) {
        float h = 0.f;
        #pragma unroll
        for (int b = 0; b < NBASIS; ++b) h += rbv[b] * sW1[k * NBASIS + b];
        h = silu_f(h);
        #pragma unroll
        for (int j = 0; j < NH; ++j) acc[j] += h * sW2[k * NH + j];
    }
    #pragma unroll
    for (int j = 0; j < NH; ++j) acc[j] = silu_f(acc[j]);   // acc = h2

    int snd = senders[e];
    int rcv = receivers[e];
    float nx = nhat[3*e+0], ny = nhat[3*e+1], nz = nhat[3*e+2];
    const float* su = s_in + (size_t)snd * NC;
    const float* vu = v_in + (size_t)snd * NC * 3;
    float* as = agg_s + (size_t)rcv * (2 * NC);
    float* av = agg_v + (size_t)rcv * (3 * NC * 3);

    #pragma unroll 1
    for (int c = 0; c < NC; ++c) {
        float w0 = 0.f, w1v = 0.f, w2v = 0.f, w3v = 0.f, w4v = 0.f;
        #pragma unroll
        for (int k = 0; k < NH; ++k) {
            float h = acc[k];
            w0  += h * sW3[(c          ) * NH + k];
            w1v += h * sW3[(NC + c     ) * NH + k];
            w2v += h * sW3[(2*NC + c   ) * NH + k];
            w3v += h * sW3[(3*NC + c   ) * NH + k];
            w4v += h * sW3[(4*NC + c   ) * NH + k];
        }
        float sc = su[c];
        float v0 = vu[3*c+0], v1 = vu[3*c+1], v2 = vu[3*c+2];
        float ndv = nx*v0 + ny*v1 + nz*v2;

        atomicAdd(&as[c],      w0  * sc);
        atomicAdd(&as[NC + c], w1v * ndv);

        float t2 = w2v * sc;
        atomicAdd(&av[3*c+0], t2 * nx);
        atomicAdd(&av[3*c+1], t2 * ny);
        atomicAdd(&av[3*c+2], t2 * nz);

        atomicAdd(&av[3*(NC + c)+0], w3v * v0);
        atomicAdd(&av[3*(NC + c)+1], w3v * v1);
        atomicAdd(&av[3*(NC + c)+2], w3v * v2);

        atomicAdd(&av[3*(2*NC + c)+0], w4v * (nx*ndv - v0 * (1.f/3.f)));
        atomicAdd(&av[3*(2*NC + c)+1], w4v * (ny*ndv - v1 * (1.f/3.f)));
        atomicAdd(&av[3*(2*NC + c)+2], w4v * (nz*ndv - v2 * (1.f/3.f)));
    }
}

// ---------------------------------------------------------------- node update
// 64 threads per node: lane k computes sg[k]; lanes 0..31 also do the vector part
__global__ __launch_bounds__(256) void node_kernel(
    const int* __restrict__ specie,
    const float* __restrict__ agg_s, const float* __restrict__ agg_v,
    const float* __restrict__ s_in,  const float* __restrict__ v_in,
    const float* __restrict__ wls,   // [64][64]
    const float* __restrict__ wlv,   // [96][32]
    const float* __restrict__ wscs,  // [5][32][64]
    const float* __restrict__ wscv,  // [5][32][32]
    float* __restrict__ s_out, float* __restrict__ v_out)
{
    int t = blockIdx.x * blockDim.x + threadIdx.x;
    int n = t >> 6;
    int k = t & 63;
    if (n >= NNODES) return;
    int sp = specie[n];

    const float* as   = agg_s + (size_t)n * 64;
    const float* sold = s_in  + (size_t)n * NC;

    float sg = 0.f;
    #pragma unroll 1
    for (int j = 0; j < 64; ++j) sg += as[j] * wls[j * 64 + k];
    sg *= INV_AVG;
    const float* ws = wscs + (size_t)sp * NC * 64;
    #pragma unroll 1
    for (int j = 0; j < NC; ++j) sg += sold[j] * ws[j * 64 + k];

    float act = silu_f(sg);
    float gate = __shfl(act, (k & 31) + 32);   // gate for channel (k&31)

    if (k < NC) {
        int c = k;
        const float* av = agg_v + (size_t)n * 288;
        float vn0 = 0.f, vn1 = 0.f, vn2 = 0.f;
        #pragma unroll 1
        for (int p = 0; p < 96; ++p) {
            float w = wlv[p * NC + c];
            vn0 += av[3*p+0] * w;
            vn1 += av[3*p+1] * w;
            vn2 += av[3*p+2] * w;
        }
        vn0 *= INV_AVG; vn1 *= INV_AVG; vn2 *= INV_AVG;
        const float* wv   = wscv + (size_t)sp * NC * NC;
        const float* vold = v_in + (size_t)n * NC * 3;
        #pragma unroll 1
        for (int j = 0; j < NC; ++j) {
            float w = wv[j * NC + c];
            vn0 += vold[3*j+0] * w;
            vn1 += vold[3*j+1] * w;
            vn2 += vold[3*j+2] * w;
        }
        s_out[(size_t)n * NC + c] = act;
        v_out[(size_t)n * NC * 3 + 3*c+0] = gate * vn0;
        v_out[(size_t)n * NC * 3 + 3*c+1] = gate * vn1;
        v_out[(size_t)n * NC * 3 + 3*c+2] = gate * vn2;
    }
}

// ---------------------------------------------------------------- output head
__global__ void out_kernel(const float* __restrict__ s,
                           const float* __restrict__ w1,  // [32][16]
                           const float* __restrict__ w2,  // [16][1]
                           float* __restrict__ out) {
    int n = blockIdx.x * blockDim.x + threadIdx.x;
    if (n >= NNODES) return;
    float sv[NC];
    #pragma unroll
    for (int c = 0; c < NC; ++c) sv[c] = s[(size_t)n * NC + c];
    float e = 0.f;
    #pragma unroll
    for (int j = 0; j < 16; ++j) {
        float tj = 0.f;
        #pragma unroll
        for (int c = 0; c < NC; ++c) tj += sv[c] * w1[c * 16 + j];
        e += tj * w2[j];
    }
    out[n] = e;
}

// ---------------------------------------------------------------- launcher
extern "C" void kernel_launch(void* const* d_in, const int* in_sizes, int n_in,
                              void* d_out, int out_size, void* d_ws, size_t ws_size,
                              hipStream_t stream) {
    const float* vectors   = (const float*)d_in[0];
    const int*   specie    = (const int*)  d_in[1];
    const int*   senders   = (const int*)  d_in[2];
    const int*   receivers = (const int*)  d_in[3];
    const float* emb       = (const float*)d_in[4];
    const float* w_rad1    = (const float*)d_in[5];
    const float* w_rad2    = (const float*)d_in[6];
    const float* w_rad_out = (const float*)d_in[7];
    const float* w_lin_s   = (const float*)d_in[8];
    const float* w_lin_v   = (const float*)d_in[9];
    const float* w_sc_s    = (const float*)d_in[10];
    const float* w_sc_v    = (const float*)d_in[11];
    const float* w_out1    = (const float*)d_in[12];
    const float* w_out2    = (const float*)d_in[13];

    float* p = (float*)d_ws;
    float* nhat = p; p += (size_t)NEDGES * 3;
    float* rb   = p; p += (size_t)NEDGES * NBASIS;
    float* s_a  = p; p += (size_t)NNODES * NC;
    float* v_a  = p; p += (size_t)NNODES * NC * 3;
    float* s_b  = p; p += (size_t)NNODES * NC;
    float* v_b  = p; p += (size_t)NNODES * NC * 3;
    float* aggs = p; p += (size_t)NNODES * 2 * NC;
    float* aggv = p; p += (size_t)NNODES * 3 * NC * 3;

    geom_kernel<<<(NEDGES + 255) / 256, 256, 0, stream>>>(vectors, nhat, rb);
    init_kernel<<<(NNODES * NC + 255) / 256, 256, 0, stream>>>(specie, emb, s_a);
    hipMemsetAsync(v_a, 0, (size_t)NNODES * NC * 3 * sizeof(float), stream);

    float* si = s_a; float* vi = v_a; float* so = s_b; float* vo = v_b;
    for (int l = 0; l < NL; ++l) {
        hipMemsetAsync(aggs, 0, (size_t)NNODES * 2 * NC * sizeof(float), stream);
        hipMemsetAsync(aggv, 0, (size_t)NNODES * 3 * NC * 3 * sizeof(float), stream);
        edge_kernel<<<(NEDGES + 255) / 256, 256, 0, stream>>>(
            rb, nhat, senders, receivers, si, vi,
            w_rad1 + (size_t)l * NBASIS * NH,
            w_rad2 + (size_t)l * NH * NH,
            w_rad_out + (size_t)l * NH * NOUT,
            aggs, aggv);
        node_kernel<<<(NNODES * 64 + 255) / 256, 256, 0, stream>>>(
            specie, aggs, aggv, si, vi,
            w_lin_s + (size_t)l * 64 * 64,
            w_lin_v + (size_t)l * 96 * 32,
            w_sc_s + (size_t)l * NSPEC * NC * 64,
            w_sc_v + (size_t)l * NSPEC * NC * NC,
            so, vo);
        float* ts = si; si = so; so = ts;
        float* tv = vi; vi = vo; vo = tv;
    }

    out_kernel<<<(NNODES + 255) / 256, 256, 0, stream>>>(si, w_out1, w_out2, (float*)d_out);
}

// Round 2
// 4975.333 us; speedup vs baseline: 5.2707x; 5.2707x over previous
//
#include <hip/hip_runtime.h>
#include <math.h>

#define NNODES 30000
#define NEDGES 480000
#define NC 32
#define NL 3
#define NH 64
#define NBASIS 8
#define NSPEC 5
#define INV_AVG 0.0625f   // 1 / AVG_NEIGH

__device__ __forceinline__ float silu_f(float x) {
    return x / (1.f + __expf(-x));
}
__device__ __forceinline__ float rdlane(float v, int k) {
    return __uint_as_float(__builtin_amdgcn_readlane(__float_as_uint(v), k));
}

// ---------------------------------------------------------------- geometry
__global__ void geom_kernel(const float* __restrict__ vec,
                            float* __restrict__ nhat4,   // [E][4]
                            float* __restrict__ rb) {    // [E][8]
    int e = blockIdx.x * blockDim.x + threadIdx.x;
    if (e >= NEDGES) return;
    float vx = vec[3*e+0] * 0.25f;   // vectors / R_MAX
    float vy = vec[3*e+1] * 0.25f;
    float vz = vec[3*e+2] * 0.25f;
    float len = sqrtf(vx*vx + vy*vy + vz*vz);      // scaled length
    float inv = 1.f / fmaxf(len, 1e-9f);
    float4 nh = make_float4(vx*inv, vy*inv, vz*inv, 0.f);
    *(float4*)(nhat4 + (size_t)e*4) = nh;
    float x = len * 0.25f;                         // lengths / R_MAX (again)
    float x3 = x*x*x;
    float x6 = x3*x3;
    float x7 = x6*x;
    float x8 = x7*x;
    float env = (x < 1.f) ? (1.f - 28.f*x6 + 48.f*x7 - 21.f*x8) : 0.f;
    float scale = 0.7071067811865476f * inv * env; // sqrt(2/R_MAX)/max(len,eps)*env
    #pragma unroll
    for (int i = 0; i < NBASIS; ++i) {
        rb[NBASIS*e + i] = scale * sinf((float)(i+1) * 3.14159265358979f * x);
    }
}

// ---------------------------------------------------------------- CSR build
__global__ void count_kernel(const int* __restrict__ receivers, int* __restrict__ deg) {
    int e = blockIdx.x * blockDim.x + threadIdx.x;
    if (e >= NEDGES) return;
    atomicAdd(&deg[receivers[e]], 1);
}

__global__ void scan_kernel(const int* __restrict__ deg, int* __restrict__ rowstart) {
    __shared__ int lsum[256];
    __shared__ int loff[256];
    int t = threadIdx.x;
    int lo = t * 118;
    int hi = min(lo + 118, NNODES);
    int s = 0;
    for (int i = lo; i < hi; ++i) s += deg[i];
    lsum[t] = s;
    __syncthreads();
    if (t == 0) {
        int run = 0;
        for (int i = 0; i < 256; ++i) { loff[i] = run; run += lsum[i]; }
    }
    __syncthreads();
    int run = loff[t];
    for (int i = lo; i < hi; ++i) { rowstart[i] = run; run += deg[i]; }
    if (t == 0) rowstart[NNODES] = NEDGES;
}

__global__ void copy_cursor_kernel(const int* __restrict__ rowstart, int* __restrict__ cursor) {
    int i = blockIdx.x * blockDim.x + threadIdx.x;
    if (i < NNODES) cursor[i] = rowstart[i];
}

__global__ void fill_kernel(const int* __restrict__ receivers,
                            int* __restrict__ cursor, int* __restrict__ edge_order) {
    int e = blockIdx.x * blockDim.x + threadIdx.x;
    if (e >= NEDGES) return;
    int pos = atomicAdd(&cursor[receivers[e]], 1);
    edge_order[pos] = e;
}

// ---------------------------------------------------------------- node init
__global__ void init_kernel(const int* __restrict__ specie,
                            const float* __restrict__ emb,
                            float* __restrict__ s) {
    int t = blockIdx.x * blockDim.x + threadIdx.x;
    if (t >= NNODES * NC) return;
    int n = t >> 5;
    int c = t & 31;
    s[t] = emb[specie[n] * NC + c];
}

// ---------------------------------------------------------------- gather pass
// One 64-lane wave per node. Lane layout: c = lane&31, half = lane>>5.
// Per edge: h1[lane] -> h2[lane] (readlane broadcast) -> 3 dots/lane from LDS W3:
//   half0: {path0, path2, path4};  half1: {path1, path3, path4(discarded)}
// TP accumulated in registers; stored once per node. NO atomics.
__global__ __launch_bounds__(512) void gather_kernel(
    const float* __restrict__ rb, const float* __restrict__ nhat4,
    const int* __restrict__ senders, const int* __restrict__ edge_order,
    const int* __restrict__ rowstart, const int* __restrict__ deg,
    const float* __restrict__ s_in, const float* __restrict__ v_in,  // v: [N][3][32]
    const float* __restrict__ w1,   // [8][64]
    const float* __restrict__ w2,   // [64][64]
    const float* __restrict__ w3,   // [64][160]
    float* __restrict__ agg_s,      // [N][64]
    float* __restrict__ agg_v)      // [N][96][3]
{
    __shared__ float sW2[NH * NH];       // [k][j]
    __shared__ float sW3[NH * 160];      // [k][o]

    for (int i = threadIdx.x; i < NH * NH;  i += 512) sW2[i] = w2[i];
    for (int i = threadIdx.x; i < NH * 160; i += 512) sW3[i] = w3[i];
    __syncthreads();

    int lane = threadIdx.x & 63;
    int wid  = threadIdx.x >> 6;
    int n = blockIdx.x * 8 + wid;
    if (n >= NNODES) return;

    int c = lane & 31;
    int half = lane >> 5;

    float w1r[8];
    #pragma unroll
    for (int b = 0; b < 8; ++b) w1r[b] = w1[b * NH + lane];

    float accS = 0.f;
    float aVa0 = 0.f, aVa1 = 0.f, aVa2 = 0.f;   // half0: path2, half1: path3
    float aVb0 = 0.f, aVb1 = 0.f, aVb2 = 0.f;   // half0: path4, half1: garbage

    int start = rowstart[n];
    int cnt   = deg[n];

    for (int i = 0; i < cnt; ++i) {
        int e   = edge_order[start + i];
        int snd = senders[e];
        float4 nh  = *(const float4*)(nhat4 + (size_t)e * 4);
        float4 rba = *(const float4*)(rb + (size_t)e * 8);
        float4 rbb = *(const float4*)(rb + (size_t)e * 8 + 4);

        // h1[lane]
        float h1v;
        h1v = rba.x * w1r[0];
        h1v = fmaf(rba.y, w1r[1], h1v);
        h1v = fmaf(rba.z, w1r[2], h1v);
        h1v = fmaf(rba.w, w1r[3], h1v);
        h1v = fmaf(rbb.x, w1r[4], h1v);
        h1v = fmaf(rbb.y, w1r[5], h1v);
        h1v = fmaf(rbb.z, w1r[6], h1v);
        h1v = fmaf(rbb.w, w1r[7], h1v);
        h1v = silu_f(h1v);

        // h2[lane] = silu( sum_k h1[k] * W2[k][lane] )
        float a0 = 0.f, a1 = 0.f;
        #pragma unroll
        for (int k = 0; k < NH; k += 2) {
            a0 = fmaf(rdlane(h1v, k),     sW2[k * NH + lane],       a0);
            a1 = fmaf(rdlane(h1v, k + 1), sW2[(k + 1) * NH + lane], a1);
        }
        float h2v = silu_f(a0 + a1);

        // three dots per lane from W3 rows
        float d0a = 0.f, d0b = 0.f, d1a = 0.f, d1b = 0.f, d2a = 0.f, d2b = 0.f;
        #pragma unroll
        for (int k = 0; k < NH; k += 2) {
            float hA = rdlane(h2v, k);
            float hB = rdlane(h2v, k + 1);
            d0a = fmaf(hA, sW3[k * 160 + lane],            d0a);
            d1a = fmaf(hA, sW3[k * 160 + 64 + lane],       d1a);
            d2a = fmaf(hA, sW3[k * 160 + 128 + c],         d2a);
            d0b = fmaf(hB, sW3[(k + 1) * 160 + lane],      d0b);
            d1b = fmaf(hB, sW3[(k + 1) * 160 + 64 + lane], d1b);
            d2b = fmaf(hB, sW3[(k + 1) * 160 + 128 + c],   d2b);
        }
        float d0 = d0a + d0b;   // half0: wgt0[c]  half1: wgt1[c]
        float d1 = d1a + d1b;   // half0: wgt2[c]  half1: wgt3[c]
        float d2 = d2a + d2b;   // both:  wgt4[c]  (half1 discards)

        // sender features
        float su = s_in[(size_t)snd * NC + c];
        float v0 = v_in[(size_t)snd * 96 + c];
        float v1 = v_in[(size_t)snd * 96 + 32 + c];
        float v2 = v_in[(size_t)snd * 96 + 64 + c];
        float ndv = nh.x * v0;
        ndv = fmaf(nh.y, v1, ndv);
        ndv = fmaf(nh.z, v2, ndv);

        // branchless TP accumulate
        float sSel = half ? ndv : su;          // path0 vs path1 multiplier
        accS = fmaf(d0, sSel, accS);
        float scale = half ? d1 : d1 * su;     // path3: d3 ; path2: d2*su
        float f0 = half ? v0 : nh.x;
        float f1 = half ? v1 : nh.y;
        float f2 = half ? v2 : nh.z;
        aVa0 = fmaf(scale, f0, aVa0);
        aVa1 = fmaf(scale, f1, aVa1);
        aVa2 = fmaf(scale, f2, aVa2);
        float m4 = half ? 0.f : d2;            // path4 only on half0
        aVb0 = fmaf(m4, fmaf(nh.x, ndv, -v0 * (1.f / 3.f)), aVb0);
        aVb1 = fmaf(m4, fmaf(nh.y, ndv, -v1 * (1.f / 3.f)), aVb1);
        aVb2 = fmaf(m4, fmaf(nh.z, ndv, -v2 * (1.f / 3.f)), aVb2);
    }

    agg_s[(size_t)n * 64 + lane] = accS;
    float* av = agg_v + (size_t)n * 288;
    if (half == 0) {
        av[c * 3 + 0] = aVa0; av[c * 3 + 1] = aVa1; av[c * 3 + 2] = aVa2;            // path2
        av[(64 + c) * 3 + 0] = aVb0; av[(64 + c) * 3 + 1] = aVb1; av[(64 + c) * 3 + 2] = aVb2; // path4
    } else {
        av[(32 + c) * 3 + 0] = aVa0; av[(32 + c) * 3 + 1] = aVa1; av[(32 + c) * 3 + 2] = aVa2; // path3
    }
}

// ---------------------------------------------------------------- node update
// 64 threads per node: lane k computes sg[k]; lanes 0..31 also do the vector part
// v layout: [N][3][32]
__global__ __launch_bounds__(256) void node_kernel(
    const int* __restrict__ specie,
    const float* __restrict__ agg_s, const float* __restrict__ agg_v,
    const float* __restrict__ s_in,  const float* __restrict__ v_in,
    const float* __restrict__ wls,   // [64][64]
    const float* __restrict__ wlv,   // [96][32]
    const float* __restrict__ wscs,  // [5][32][64]
    const float* __restrict__ wscv,  // [5][32][32]
    float* __restrict__ s_out, float* __restrict__ v_out)
{
    int t = blockIdx.x * blockDim.x + threadIdx.x;
    int n = t >> 6;
    int k = t & 63;
    if (n >= NNODES) return;
    int sp = specie[n];

    const float* as   = agg_s + (size_t)n * 64;
    const float* sold = s_in  + (size_t)n * NC;

    float sg = 0.f;
    #pragma unroll 1
    for (int j = 0; j < 64; ++j) sg += as[j] * wls[j * 64 + k];
    sg *= INV_AVG;
    const float* ws = wscs + (size_t)sp * NC * 64;
    #pragma unroll 1
    for (int j = 0; j < NC; ++j) sg += sold[j] * ws[j * 64 + k];

    float act = silu_f(sg);
    float gate = __shfl(act, (k & 31) + 32);   // gate for channel (k&31)

    if (k < NC) {
        int c = k;
        const float* av = agg_v + (size_t)n * 288;
        float vn0 = 0.f, vn1 = 0.f, vn2 = 0.f;
        #pragma unroll 1
        for (int p = 0; p < 96; ++p) {
            float w = wlv[p * NC + c];
            vn0 += av[3*p+0] * w;
            vn1 += av[3*p+1] * w;
            vn2 += av[3*p+2] * w;
        }
        vn0 *= INV_AVG; vn1 *= INV_AVG; vn2 *= INV_AVG;
        const float* wv   = wscv + (size_t)sp * NC * NC;
        const float* vold = v_in + (size_t)n * 96;
        #pragma unroll 1
        for (int j = 0; j < NC; ++j) {
            float w = wv[j * NC + c];
            vn0 += vold[j]      * w;
            vn1 += vold[32 + j] * w;
            vn2 += vold[64 + j] * w;
        }
        s_out[(size_t)n * NC + c] = act;
        v_out[(size_t)n * 96 + c]      = gate * vn0;
        v_out[(size_t)n * 96 + 32 + c] = gate * vn1;
        v_out[(size_t)n * 96 + 64 + c] = gate * vn2;
    }
}

// ---------------------------------------------------------------- output head
__global__ void out_kernel(const float* __restrict__ s,
                           const float* __restrict__ w1,  // [32][16]
                           const float* __restrict__ w2,  // [16][1]
                           float* __restrict__ out) {
    int n = blockIdx.x * blockDim.x + threadIdx.x;
    if (n >= NNODES) return;
    float sv[NC];
    #pragma unroll
    for (int c = 0; c < NC; ++c) sv[c] = s[(size_t)n * NC + c];
    float e = 0.f;
    #pragma unroll
    for (int j = 0; j < 16; ++j) {
        float tj = 0.f;
        #pragma unroll
        for (int c = 0; c < NC; ++c) tj += sv[c] * w1[c * 16 + j];
        e += tj * w2[j];
    }
    out[n] = e;
}

// ---------------------------------------------------------------- launcher
extern "C" void kernel_launch(void* const* d_in, const int* in_sizes, int n_in,
                              void* d_out, int out_size, void* d_ws, size_t ws_size,
                              hipStream_t stream) {
    const float* vectors   = (const float*)d_in[0];
    const int*   specie    = (const int*)  d_in[1];
    const int*   senders   = (const int*)  d_in[2];
    const int*   receivers = (const int*)  d_in[3];
    const float* emb       = (const float*)d_in[4];
    const float* w_rad1    = (const float*)d_in[5];
    const float* w_rad2    = (const float*)d_in[6];
    const float* w_rad_out = (const float*)d_in[7];
    const float* w_lin_s   = (const float*)d_in[8];
    const float* w_lin_v   = (const float*)d_in[9];
    const float* w_sc_s    = (const float*)d_in[10];
    const float* w_sc_v    = (const float*)d_in[11];
    const float* w_out1    = (const float*)d_in[12];
    const float* w_out2    = (const float*)d_in[13];

    float* p = (float*)d_ws;
    float* nhat4 = p; p += (size_t)NEDGES * 4;
    float* rb    = p; p += (size_t)NEDGES * NBASIS;
    float* s_a   = p; p += (size_t)NNODES * NC;
    float* v_a   = p; p += (size_t)NNODES * NC * 3;
    float* s_b   = p; p += (size_t)NNODES * NC;
    float* v_b   = p; p += (size_t)NNODES * NC * 3;
    float* aggs  = p; p += (size_t)NNODES * 2 * NC;
    float* aggv  = p; p += (size_t)NNODES * 3 * NC * 3;
    int* deg        = (int*)p; p += NNODES;          // reuse as int storage
    int* rowstart   = (int*)p; p += NNODES + 4;
    int* cursor     = (int*)p; p += NNODES;
    int* edge_order = (int*)p; p += NEDGES;

    // geometry + CSR (once; graph static across layers)
    geom_kernel<<<(NEDGES + 255) / 256, 256, 0, stream>>>(vectors, nhat4, rb);
    hipMemsetAsync(deg, 0, NNODES * sizeof(int), stream);
    count_kernel<<<(NEDGES + 255) / 256, 256, 0, stream>>>(receivers, deg);
    scan_kernel<<<1, 256, 0, stream>>>(deg, rowstart);
    copy_cursor_kernel<<<(NNODES + 255) / 256, 256, 0, stream>>>(rowstart, cursor);
    fill_kernel<<<(NEDGES + 255) / 256, 256, 0, stream>>>(receivers, cursor, edge_order);

    init_kernel<<<(NNODES * NC + 255) / 256, 256, 0, stream>>>(specie, emb, s_a);
    hipMemsetAsync(v_a, 0, (size_t)NNODES * NC * 3 * sizeof(float), stream);

    float* si = s_a; float* vi = v_a; float* so = s_b; float* vo = v_b;
    for (int l = 0; l < NL; ++l) {
        gather_kernel<<<NNODES / 8, 512, 0, stream>>>(
            rb, nhat4, senders, edge_order, rowstart, deg, si, vi,
            w_rad1 + (size_t)l * NBASIS * NH,
            w_rad2 + (size_t)l * NH * NH,
            w_rad_out + (size_t)l * NH * 160,
            aggs, aggv);
        node_kernel<<<(NNODES * 64 + 255) / 256, 256, 0, stream>>>(
            specie, aggs, aggv, si, vi,
            w_lin_s + (size_t)l * 64 * 64,
            w_lin_v + (size_t)l * 96 * 32,
            w_sc_s + (size_t)l * NSPEC * NC * 64,
            w_sc_v + (size_t)l * NSPEC * NC * NC,
            so, vo);
        float* ts = si; si = so; so = ts;
        float* tv = vi; vi = vo; vo = tv;
    }

    out_kernel<<<(NNODES + 255) / 256, 256, 0, stream>>>(si, w_out1, w_out2, (float*)d_out);
}

// Round 6
// 3967.257 us; speedup vs baseline: 6.6100x; 1.2541x over previous
//
#include <hip/hip_runtime.h>
#include <math.h>

#define NNODES 30000
#define NEDGES 480000
#define NC 32
#define NL 3
#define NH 64
#define NBASIS 8
#define NSPEC 5
#define INV_AVG 0.0625f   // 1 / AVG_NEIGH

__device__ __forceinline__ float silu_f(float x) {
    return x / (1.f + __expf(-x));
}
__device__ __forceinline__ float rdlane(float v, int k) {
    return __uint_as_float(__builtin_amdgcn_readlane(__float_as_uint(v), k));
}

// ---------------------------------------------------------------- geometry
__global__ void geom_kernel(const float* __restrict__ vec,
                            float* __restrict__ nhat4,   // [E][4]
                            float* __restrict__ rb) {    // [E][8]
    int e = blockIdx.x * blockDim.x + threadIdx.x;
    if (e >= NEDGES) return;
    float vx = vec[3*e+0] * 0.25f;   // vectors / R_MAX
    float vy = vec[3*e+1] * 0.25f;
    float vz = vec[3*e+2] * 0.25f;
    float len = sqrtf(vx*vx + vy*vy + vz*vz);      // scaled length
    float inv = 1.f / fmaxf(len, 1e-9f);
    float4 nh = make_float4(vx*inv, vy*inv, vz*inv, 0.f);
    *(float4*)(nhat4 + (size_t)e*4) = nh;
    float x = len * 0.25f;                         // lengths / R_MAX (again)
    float x3 = x*x*x;
    float x6 = x3*x3;
    float x7 = x6*x;
    float x8 = x7*x;
    float env = (x < 1.f) ? (1.f - 28.f*x6 + 48.f*x7 - 21.f*x8) : 0.f;
    float scale = 0.7071067811865476f * inv * env; // sqrt(2/R_MAX)/max(len,eps)*env
    #pragma unroll
    for (int i = 0; i < NBASIS; ++i) {
        rb[NBASIS*e + i] = scale * sinf((float)(i+1) * 3.14159265358979f * x);
    }
}

// ---------------------------------------------------------------- CSR build
__global__ void count_kernel(const int* __restrict__ receivers, int* __restrict__ deg) {
    int e = blockIdx.x * blockDim.x + threadIdx.x;
    if (e >= NEDGES) return;
    atomicAdd(&deg[receivers[e]], 1);
}

__global__ void scan_kernel(const int* __restrict__ deg, int* __restrict__ rowstart) {
    __shared__ int lsum[256];
    __shared__ int loff[256];
    int t = threadIdx.x;
    int lo = t * 118;
    int hi = min(lo + 118, NNODES);
    int s = 0;
    for (int i = lo; i < hi; ++i) s += deg[i];
    lsum[t] = s;
    __syncthreads();
    if (t == 0) {
        int run = 0;
        for (int i = 0; i < 256; ++i) { loff[i] = run; run += lsum[i]; }
    }
    __syncthreads();
    int run = loff[t];
    for (int i = lo; i < hi; ++i) { rowstart[i] = run; run += deg[i]; }
    if (t == 0) rowstart[NNODES] = NEDGES;
}

__global__ void copy_cursor_kernel(const int* __restrict__ rowstart, int* __restrict__ cursor) {
    int i = blockIdx.x * blockDim.x + threadIdx.x;
    if (i < NNODES) cursor[i] = rowstart[i];
}

__global__ void fill_kernel(const int* __restrict__ receivers,
                            int* __restrict__ cursor, int* __restrict__ edge_order) {
    int e = blockIdx.x * blockDim.x + threadIdx.x;
    if (e >= NEDGES) return;
    int pos = atomicAdd(&cursor[receivers[e]], 1);
    edge_order[pos] = e;
}

// ---------------------------------------------------------------- permute edge data (once)
__global__ void perm_kernel(const int* __restrict__ edge_order,
                            const int* __restrict__ senders,
                            const float* __restrict__ nhat4,
                            float* __restrict__ nh_perm, int* __restrict__ snd_perm) {
    int i = blockIdx.x * blockDim.x + threadIdx.x;
    if (i >= NEDGES) return;
    int e = edge_order[i];
    *(float4*)(nh_perm + (size_t)i*4) = *(const float4*)(nhat4 + (size_t)e*4);
    snd_perm[i] = senders[e];
}

// ---------------------------------------------------------------- weight transpose (once)
// w1t[l][k][b] from w_rad1[l][b][k];  w3t[l][o][k] from w_rad_out[l][k][o]
__global__ void transw_kernel(const float* __restrict__ w1, const float* __restrict__ w3,
                              float* __restrict__ w1t, float* __restrict__ w3t) {
    int t = blockIdx.x * blockDim.x + threadIdx.x;
    if (t < NL * 64 * 8) {
        int l = t / 512, r = t % 512, k = r >> 3, b = r & 7;
        w1t[t] = w1[l * 512 + b * 64 + k];
    }
    int u = t - NL * 64 * 8;
    if (u >= 0 && u < NL * 160 * 64) {
        int l = u / 10240, r = u % 10240, o = r >> 6, k = r & 63;
        w3t[u] = w3[l * 10240 + k * 160 + o];
    }
}

// ---------------------------------------------------------------- node init
__global__ void init_kernel(const int* __restrict__ specie,
                            const float* __restrict__ emb,
                            float* __restrict__ s) {
    int t = blockIdx.x * blockDim.x + threadIdx.x;
    if (t >= NNODES * NC) return;
    int n = t >> 5;
    int c = t & 31;
    s[t] = emb[specie[n] * NC + c];
}

// ---------------------------------------------------------------- per-edge radial MLP
// Thread-per-edge (receiver-sorted order i). Weights read at wave-uniform
// addresses -> scalar s_load broadcast. 64 fp32 accumulators; h1 recomputed
// on the fly (no runtime register indexing). Output wgt[i][160] in fp16.
__global__ __launch_bounds__(256) void mlp_kernel(
    const float* __restrict__ rb,          // [E][8] original order
    const int* __restrict__ edge_order,    // [E]
    const float* __restrict__ w1t,         // [64][8]
    const float* __restrict__ w2,          // [64][64]
    const float* __restrict__ w3t,         // [160][64]
    _Float16* __restrict__ wgt16)          // [E][160] permuted order
{
    int i = blockIdx.x * 256 + threadIdx.x;
    if (i >= NEDGES) return;
    int e = edge_order[i];
    float4 ra = *(const float4*)(rb + (size_t)e * 8);
    float4 rv = *(const float4*)(rb + (size_t)e * 8 + 4);

    float acc[NH];
    #pragma unroll
    for (int j = 0; j < NH; ++j) acc[j] = 0.f;

    #pragma unroll 1
    for (int k = 0; k < NH; ++k) {
        const float* w1k = w1t + k * 8;
        float h;
        h = ra.x * w1k[0];
        h = fmaf(ra.y, w1k[1], h);
        h = fmaf(ra.z, w1k[2], h);
        h = fmaf(ra.w, w1k[3], h);
        h = fmaf(rv.x, w1k[4], h);
        h = fmaf(rv.y, w1k[5], h);
        h = fmaf(rv.z, w1k[6], h);
        h = fmaf(rv.w, w1k[7], h);
        h = silu_f(h);
        const float* w2k = w2 + k * NH;
        #pragma unroll
        for (int j = 0; j < NH; ++j) acc[j] = fmaf(h, w2k[j], acc[j]);
    }
    #pragma unroll
    for (int j = 0; j < NH; ++j) acc[j] = silu_f(acc[j]);   // acc = h2

    _Float16* wp = wgt16 + (size_t)i * 160;
    #pragma unroll 1
    for (int ob = 0; ob < 160; ob += 8) {
        float t0[8], t1[8];
        #pragma unroll
        for (int o = 0; o < 8; ++o) { t0[o] = 0.f; t1[o] = 0.f; }
        #pragma unroll
        for (int o = 0; o < 8; ++o) {
            const float* wr = w3t + (ob + o) * NH;
            #pragma unroll
            for (int k = 0; k < NH; k += 2) {
                t0[o] = fmaf(acc[k],     wr[k],     t0[o]);
                t1[o] = fmaf(acc[k + 1], wr[k + 1], t1[o]);
            }
        }
        union { _Float16 h[8]; uint4 u; } pk;
        #pragma unroll
        for (int o = 0; o < 8; ++o)
            pk.h[o] = (_Float16)(t0[o] + t1[o]);
        *(uint4*)(wp + ob) = pk.u;
    }
}

// ---------------------------------------------------------------- gather + TP
// One 64-lane wave per node; all edge data pre-permuted & coalesced. No LDS.
__global__ __launch_bounds__(512) void gather_tp_kernel(
    const _Float16* __restrict__ wgt16,   // [E][160]
    const float* __restrict__ nh_perm,    // [E][4]
    const int* __restrict__ snd_perm,     // [E]
    const int* __restrict__ rowstart, const int* __restrict__ deg,
    const float* __restrict__ s_in, const float* __restrict__ v_in,  // v: [N][3][32]
    float* __restrict__ agg_s,      // [N][64]
    float* __restrict__ agg_v)      // [N][96][3]
{
    int lane = threadIdx.x & 63;
    int wid  = threadIdx.x >> 6;
    int n = blockIdx.x * 8 + wid;
    if (n >= NNODES) return;

    int c = lane & 31;
    int half = lane >> 5;
    int off01 = half * 32 + c;

    float accS = 0.f;
    float aVa0 = 0.f, aVa1 = 0.f, aVa2 = 0.f;   // half0: path2, half1: path3
    float aVb0 = 0.f, aVb1 = 0.f, aVb2 = 0.f;   // half0: path4, half1: garbage

    int start = rowstart[n];
    int cnt   = deg[n];

    for (int i = 0; i < cnt; ++i) {
        int idx = start + i;
        float4 nh = *(const float4*)(nh_perm + (size_t)idx * 4);
        int snd = snd_perm[idx];
        const _Float16* wp = wgt16 + (size_t)idx * 160;

        float d0  = (float)wp[off01];        // half0: wgt0[c]  half1: wgt1[c]
        float d1  = (float)wp[64 + off01];   // half0: wgt2[c]  half1: wgt3[c]
        float d2f = (float)wp[128 + c];      // wgt4[c] (half1 discards)

        float su = s_in[(size_t)snd * NC + c];
        float v0 = v_in[(size_t)snd * 96 + c];
        float v1 = v_in[(size_t)snd * 96 + 32 + c];
        float v2 = v_in[(size_t)snd * 96 + 64 + c];
        float ndv = nh.x * v0;
        ndv = fmaf(nh.y, v1, ndv);
        ndv = fmaf(nh.z, v2, ndv);

        float sSel = half ? ndv : su;          // path1 vs path0 multiplier
        accS = fmaf(d0, sSel, accS);
        float scale = half ? d1 : d1 * su;     // path3: w3 ; path2: w2*su
        float f0 = half ? v0 : nh.x;
        float f1 = half ? v1 : nh.y;
        float f2 = half ? v2 : nh.z;
        aVa0 = fmaf(scale, f0, aVa0);
        aVa1 = fmaf(scale, f1, aVa1);
        aVa2 = fmaf(scale, f2, aVa2);
        float m4 = half ? 0.f : d2f;           // path4 only on half0
        aVb0 = fmaf(m4, fmaf(nh.x, ndv, -v0 * (1.f / 3.f)), aVb0);
        aVb1 = fmaf(m4, fmaf(nh.y, ndv, -v1 * (1.f / 3.f)), aVb1);
        aVb2 = fmaf(m4, fmaf(nh.z, ndv, -v2 * (1.f / 3.f)), aVb2);
    }

    agg_s[(size_t)n * 64 + lane] = accS;
    float* av = agg_v + (size_t)n * 288;
    if (half == 0) {
        av[c * 3 + 0] = aVa0; av[c * 3 + 1] = aVa1; av[c * 3 + 2] = aVa2;                      // path2
        av[(64 + c) * 3 + 0] = aVb0; av[(64 + c) * 3 + 1] = aVb1; av[(64 + c) * 3 + 2] = aVb2; // path4
    } else {
        av[(32 + c) * 3 + 0] = aVa0; av[(32 + c) * 3 + 1] = aVa1; av[(32 + c) * 3 + 2] = aVa2; // path3
    }
}

// ---------------------------------------------------------------- fallback gather (Round-2)
__global__ __launch_bounds__(512) void gather_kernel(
    const float* __restrict__ rb, const float* __restrict__ nhat4,
    const int* __restrict__ senders, const int* __restrict__ edge_order,
    const int* __restrict__ rowstart, const int* __restrict__ deg,
    const float* __restrict__ s_in, const float* __restrict__ v_in,
    const float* __restrict__ w1, const float* __restrict__ w2, const float* __restrict__ w3,
    float* __restrict__ agg_s, float* __restrict__ agg_v)
{
    __shared__ float sW2[NH * NH];
    __shared__ float sW3[NH * 160];
    for (int i = threadIdx.x; i < NH * NH;  i += 512) sW2[i] = w2[i];
    for (int i = threadIdx.x; i < NH * 160; i += 512) sW3[i] = w3[i];
    __syncthreads();
    int lane = threadIdx.x & 63;
    int wid  = threadIdx.x >> 6;
    int n = blockIdx.x * 8 + wid;
    if (n >= NNODES) return;
    int c = lane & 31;
    int half = lane >> 5;
    float w1r[8];
    #pragma unroll
    for (int b = 0; b < 8; ++b) w1r[b] = w1[b * NH + lane];
    float accS = 0.f;
    float aVa0 = 0.f, aVa1 = 0.f, aVa2 = 0.f;
    float aVb0 = 0.f, aVb1 = 0.f, aVb2 = 0.f;
    int start = rowstart[n];
    int cnt   = deg[n];
    for (int i = 0; i < cnt; ++i) {
        int e   = edge_order[start + i];
        int snd = senders[e];
        float4 nh  = *(const float4*)(nhat4 + (size_t)e * 4);
        float4 rba = *(const float4*)(rb + (size_t)e * 8);
        float4 rbb = *(const float4*)(rb + (size_t)e * 8 + 4);
        float h1v;
        h1v = rba.x * w1r[0];
        h1v = fmaf(rba.y, w1r[1], h1v);
        h1v = fmaf(rba.z, w1r[2], h1v);
        h1v = fmaf(rba.w, w1r[3], h1v);
        h1v = fmaf(rbb.x, w1r[4], h1v);
        h1v = fmaf(rbb.y, w1r[5], h1v);
        h1v = fmaf(rbb.z, w1r[6], h1v);
        h1v = fmaf(rbb.w, w1r[7], h1v);
        h1v = silu_f(h1v);
        float a0 = 0.f, a1 = 0.f;
        #pragma unroll
        for (int k = 0; k < NH; k += 2) {
            a0 = fmaf(rdlane(h1v, k),     sW2[k * NH + lane],       a0);
            a1 = fmaf(rdlane(h1v, k + 1), sW2[(k + 1) * NH + lane], a1);
        }
        float h2v = silu_f(a0 + a1);
        float d0a = 0.f, d0b = 0.f, d1a = 0.f, d1b = 0.f, d2a = 0.f, d2b = 0.f;
        #pragma unroll
        for (int k = 0; k < NH; k += 2) {
            float hA = rdlane(h2v, k);
            float hB = rdlane(h2v, k + 1);
            d0a = fmaf(hA, sW3[k * 160 + lane],            d0a);
            d1a = fmaf(hA, sW3[k * 160 + 64 + lane],       d1a);
            d2a = fmaf(hA, sW3[k * 160 + 128 + c],         d2a);
            d0b = fmaf(hB, sW3[(k + 1) * 160 + lane],      d0b);
            d1b = fmaf(hB, sW3[(k + 1) * 160 + 64 + lane], d1b);
            d2b = fmaf(hB, sW3[(k + 1) * 160 + 128 + c],   d2b);
        }
        float d0 = d0a + d0b;
        float d1 = d1a + d1b;
        float d2 = d2a + d2b;
        float su = s_in[(size_t)snd * NC + c];
        float v0 = v_in[(size_t)snd * 96 + c];
        float v1 = v_in[(size_t)snd * 96 + 32 + c];
        float v2 = v_in[(size_t)snd * 96 + 64 + c];
        float ndv = nh.x * v0;
        ndv = fmaf(nh.y, v1, ndv);
        ndv = fmaf(nh.z, v2, ndv);
        float sSel = half ? ndv : su;
        accS = fmaf(d0, sSel, accS);
        float scale = half ? d1 : d1 * su;
        float f0 = half ? v0 : nh.x;
        float f1 = half ? v1 : nh.y;
        float f2 = half ? v2 : nh.z;
        aVa0 = fmaf(scale, f0, aVa0);
        aVa1 = fmaf(scale, f1, aVa1);
        aVa2 = fmaf(scale, f2, aVa2);
        float m4 = half ? 0.f : d2;
        aVb0 = fmaf(m4, fmaf(nh.x, ndv, -v0 * (1.f / 3.f)), aVb0);
        aVb1 = fmaf(m4, fmaf(nh.y, ndv, -v1 * (1.f / 3.f)), aVb1);
        aVb2 = fmaf(m4, fmaf(nh.z, ndv, -v2 * (1.f / 3.f)), aVb2);
    }
    agg_s[(size_t)n * 64 + lane] = accS;
    float* av = agg_v + (size_t)n * 288;
    if (half == 0) {
        av[c * 3 + 0] = aVa0; av[c * 3 + 1] = aVa1; av[c * 3 + 2] = aVa2;
        av[(64 + c) * 3 + 0] = aVb0; av[(64 + c) * 3 + 1] = aVb1; av[(64 + c) * 3 + 2] = aVb2;
    } else {
        av[(32 + c) * 3 + 0] = aVa0; av[(32 + c) * 3 + 1] = aVa1; av[(32 + c) * 3 + 2] = aVa2;
    }
}

// ---------------------------------------------------------------- node update
__global__ __launch_bounds__(256) void node_kernel(
    const int* __restrict__ specie,
    const float* __restrict__ agg_s, const float* __restrict__ agg_v,
    const float* __restrict__ s_in,  const float* __restrict__ v_in,
    const float* __restrict__ wls,   // [64][64]
    const float* __restrict__ wlv,   // [96][32]
    const float* __restrict__ wscs,  // [5][32][64]
    const float* __restrict__ wscv,  // [5][32][32]
    float* __restrict__ s_out, float* __restrict__ v_out)
{
    int t = blockIdx.x * blockDim.x + threadIdx.x;
    int n = t >> 6;
    int k = t & 63;
    if (n >= NNODES) return;
    int sp = specie[n];

    const float* as   = agg_s + (size_t)n * 64;
    const float* sold = s_in  + (size_t)n * NC;

    float sg = 0.f;
    #pragma unroll 1
    for (int j = 0; j < 64; ++j) sg += as[j] * wls[j * 64 + k];
    sg *= INV_AVG;
    const float* ws = wscs + (size_t)sp * NC * 64;
    #pragma unroll 1
    for (int j = 0; j < NC; ++j) sg += sold[j] * ws[j * 64 + k];

    float act = silu_f(sg);
    float gate = __shfl(act, (k & 31) + 32);   // gate for channel (k&31)

    if (k < NC) {
        int c = k;
        const float* av = agg_v + (size_t)n * 288;
        float vn0 = 0.f, vn1 = 0.f, vn2 = 0.f;
        #pragma unroll 1
        for (int p = 0; p < 96; ++p) {
            float w = wlv[p * NC + c];
            vn0 += av[3*p+0] * w;
            vn1 += av[3*p+1] * w;
            vn2 += av[3*p+2] * w;
        }
        vn0 *= INV_AVG; vn1 *= INV_AVG; vn2 *= INV_AVG;
        const float* wv   = wscv + (size_t)sp * NC * NC;
        const float* vold = v_in + (size_t)n * 96;
        #pragma unroll 1
        for (int j = 0; j < NC; ++j) {
            float w = wv[j * NC + c];
            vn0 += vold[j]      * w;
            vn1 += vold[32 + j] * w;
            vn2 += vold[64 + j] * w;
        }
        s_out[(size_t)n * NC + c] = act;
        v_out[(size_t)n * 96 + c]      = gate * vn0;
        v_out[(size_t)n * 96 + 32 + c] = gate * vn1;
        v_out[(size_t)n * 96 + 64 + c] = gate * vn2;
    }
}

// ---------------------------------------------------------------- output head
__global__ void out_kernel(const float* __restrict__ s,
                           const float* __restrict__ w1,  // [32][16]
                           const float* __restrict__ w2,  // [16][1]
                           float* __restrict__ out) {
    int n = blockIdx.x * blockDim.x + threadIdx.x;
    if (n >= NNODES) return;
    float sv[NC];
    #pragma unroll
    for (int c = 0; c < NC; ++c) sv[c] = s[(size_t)n * NC + c];
    float e = 0.f;
    #pragma unroll
    for (int j = 0; j < 16; ++j) {
        float tj = 0.f;
        #pragma unroll
        for (int c = 0; c < NC; ++c) tj += sv[c] * w1[c * 16 + j];
        e += tj * w2[j];
    }
    out[n] = e;
}

// ---------------------------------------------------------------- launcher
extern "C" void kernel_launch(void* const* d_in, const int* in_sizes, int n_in,
                              void* d_out, int out_size, void* d_ws, size_t ws_size,
                              hipStream_t stream) {
    const float* vectors   = (const float*)d_in[0];
    const int*   specie    = (const int*)  d_in[1];
    const int*   senders   = (const int*)  d_in[2];
    const int*   receivers = (const int*)  d_in[3];
    const float* emb       = (const float*)d_in[4];
    const float* w_rad1    = (const float*)d_in[5];
    const float* w_rad2    = (const float*)d_in[6];
    const float* w_rad_out = (const float*)d_in[7];
    const float* w_lin_s   = (const float*)d_in[8];
    const float* w_lin_v   = (const float*)d_in[9];
    const float* w_sc_s    = (const float*)d_in[10];
    const float* w_sc_v    = (const float*)d_in[11];
    const float* w_out1    = (const float*)d_in[12];
    const float* w_out2    = (const float*)d_in[13];

    char* base = (char*)d_ws;
    size_t off = 0;
    auto alloc = [&](size_t bytes) { char* q = base + off; off += (bytes + 255) & ~(size_t)255; return q; };

    float* nhat4 = (float*)alloc((size_t)NEDGES * 4 * 4);
    float* rb    = (float*)alloc((size_t)NEDGES * 8 * 4);
    float* s_a   = (float*)alloc((size_t)NNODES * NC * 4);
    float* v_a   = (float*)alloc((size_t)NNODES * NC * 3 * 4);
    float* s_b   = (float*)alloc((size_t)NNODES * NC * 4);
    float* v_b   = (float*)alloc((size_t)NNODES * NC * 3 * 4);
    float* aggs  = (float*)alloc((size_t)NNODES * 2 * NC * 4);
    float* aggv  = (float*)alloc((size_t)NNODES * 3 * NC * 3 * 4);
    int* deg        = (int*)alloc((size_t)NNODES * 4);
    int* rowstart   = (int*)alloc((size_t)(NNODES + 4) * 4);
    int* cursor     = (int*)alloc((size_t)NNODES * 4);
    int* edge_order = (int*)alloc((size_t)NEDGES * 4);
    // big-path extras
    float*    nh_perm  = (float*)alloc((size_t)NEDGES * 4 * 4);
    int*      snd_perm = (int*)alloc((size_t)NEDGES * 4);
    float*    w1t      = (float*)alloc((size_t)NL * 64 * 8 * 4);
    float*    w3t      = (float*)alloc((size_t)NL * 160 * 64 * 4);
    _Float16* wgt16    = (_Float16*)alloc((size_t)NEDGES * 160 * 2);
    bool big = (off <= ws_size);

    // geometry + CSR (once; graph static across layers)
    geom_kernel<<<(NEDGES + 255) / 256, 256, 0, stream>>>(vectors, nhat4, rb);
    (void)hipMemsetAsync(deg, 0, NNODES * sizeof(int), stream);
    count_kernel<<<(NEDGES + 255) / 256, 256, 0, stream>>>(receivers, deg);
    scan_kernel<<<1, 256, 0, stream>>>(deg, rowstart);
    copy_cursor_kernel<<<(NNODES + 255) / 256, 256, 0, stream>>>(rowstart, cursor);
    fill_kernel<<<(NEDGES + 255) / 256, 256, 0, stream>>>(receivers, cursor, edge_order);
    if (big) {
        perm_kernel<<<(NEDGES + 255) / 256, 256, 0, stream>>>(edge_order, senders, nhat4, nh_perm, snd_perm);
        transw_kernel<<<(NL * (64 * 8 + 160 * 64) + 255) / 256, 256, 0, stream>>>(w_rad1, w_rad_out, w1t, w3t);
    }

    init_kernel<<<(NNODES * NC + 255) / 256, 256, 0, stream>>>(specie, emb, s_a);
    (void)hipMemsetAsync(v_a, 0, (size_t)NNODES * NC * 3 * sizeof(float), stream);

    float* si = s_a; float* vi = v_a; float* so = s_b; float* vo = v_b;
    for (int l = 0; l < NL; ++l) {
        if (big) {
            mlp_kernel<<<(NEDGES + 255) / 256, 256, 0, stream>>>(
                rb, edge_order,
                w1t + (size_t)l * 64 * 8,
                w_rad2 + (size_t)l * NH * NH,
                w3t + (size_t)l * 160 * 64,
                wgt16);
            gather_tp_kernel<<<NNODES / 8, 512, 0, stream>>>(
                wgt16, nh_perm, snd_perm, rowstart, deg, si, vi, aggs, aggv);
        } else {
            gather_kernel<<<NNODES / 8, 512, 0, stream>>>(
                rb, nhat4, senders, edge_order, rowstart, deg, si, vi,
                w_rad1 + (size_t)l * NBASIS * NH,
                w_rad2 + (size_t)l * NH * NH,
                w_rad_out + (size_t)l * NH * 160,
                aggs, aggv);
        }
        node_kernel<<<(NNODES * 64 + 255) / 256, 256, 0, stream>>>(
            specie, aggs, aggv, si, vi,
            w_lin_s + (size_t)l * 64 * 64,
            w_lin_v + (size_t)l * 96 * 32,
            w_sc_s + (size_t)l * NSPEC * NC * 64,
            w_sc_v + (size_t)l * NSPEC * NC * NC,
            so, vo);
        float* ts = si; si = so; so = ts;
        float* tv = vi; vi = vo; vo = tv;
    }

    out_kernel<<<(NNODES + 255) / 256, 256, 0, stream>>>(si, w_out1, w_out2, (float*)d_out);
}

// Round 7
// 1768.903 us; speedup vs baseline: 14.8248x; 2.2428x over previous
//
#include <hip/hip_runtime.h>
#include <math.h>

#define NNODES 30000
#define NEDGES 480000
#define NC 32
#define NL 3
#define NH 64
#define NBASIS 8
#define NSPEC 5
#define INV_AVG 0.0625f   // 1 / AVG_NEIGH
#define ECHUNK 240000     // NEDGES/2 — h2p chunk (aliases aggv)

typedef _Float16 half2v __attribute__((ext_vector_type(2)));
typedef unsigned int uint32;

__device__ __forceinline__ float silu_f(float x) {
    return x / (1.f + __expf(-x));
}
__device__ __forceinline__ half2v u2h(uint32 u) {
    union { uint32 u; half2v h; } x; x.u = u; return x.h;
}
__device__ __forceinline__ uint32 packh2(float a, float b) {
    union { uint32 u; half2v h; } x;
    x.h.x = (_Float16)a; x.h.y = (_Float16)b; return x.u;
}

// ---------------------------------------------------------------- geometry
__global__ void geom_kernel(const float* __restrict__ vec,
                            float* __restrict__ nhat4,   // [E][4]
                            float* __restrict__ rb) {    // [E][8]
    int e = blockIdx.x * blockDim.x + threadIdx.x;
    if (e >= NEDGES) return;
    float vx = vec[3*e+0] * 0.25f;   // vectors / R_MAX
    float vy = vec[3*e+1] * 0.25f;
    float vz = vec[3*e+2] * 0.25f;
    float len = sqrtf(vx*vx + vy*vy + vz*vz);      // scaled length
    float inv = 1.f / fmaxf(len, 1e-9f);
    float4 nh = make_float4(vx*inv, vy*inv, vz*inv, 0.f);
    *(float4*)(nhat4 + (size_t)e*4) = nh;
    float x = len * 0.25f;                         // lengths / R_MAX (again)
    float x3 = x*x*x;
    float x6 = x3*x3;
    float x7 = x6*x;
    float x8 = x7*x;
    float env = (x < 1.f) ? (1.f - 28.f*x6 + 48.f*x7 - 21.f*x8) : 0.f;
    float scale = 0.7071067811865476f * inv * env; // sqrt(2/R_MAX)/max(len,eps)*env
    #pragma unroll
    for (int i = 0; i < NBASIS; ++i) {
        rb[NBASIS*e + i] = scale * sinf((float)(i+1) * 3.14159265358979f * x);
    }
}

// ---------------------------------------------------------------- CSR build
__global__ void count_kernel(const int* __restrict__ receivers, int* __restrict__ deg) {
    int e = blockIdx.x * blockDim.x + threadIdx.x;
    if (e >= NEDGES) return;
    atomicAdd(&deg[receivers[e]], 1);
}

__global__ void scan_kernel(const int* __restrict__ deg, int* __restrict__ rowstart) {
    __shared__ int lsum[256];
    __shared__ int loff[256];
    int t = threadIdx.x;
    int lo = t * 118;
    int hi = min(lo + 118, NNODES);
    int s = 0;
    for (int i = lo; i < hi; ++i) s += deg[i];
    lsum[t] = s;
    __syncthreads();
    if (t == 0) {
        int run = 0;
        for (int i = 0; i < 256; ++i) { loff[i] = run; run += lsum[i]; }
    }
    __syncthreads();
    int run = loff[t];
    for (int i = lo; i < hi; ++i) { rowstart[i] = run; run += deg[i]; }
    if (t == 0) rowstart[NNODES] = NEDGES;
}

__global__ void copy_cursor_kernel(const int* __restrict__ rowstart, int* __restrict__ cursor) {
    int i = blockIdx.x * blockDim.x + threadIdx.x;
    if (i < NNODES) cursor[i] = rowstart[i];
}

__global__ void fill_kernel(const int* __restrict__ receivers,
                            int* __restrict__ cursor, int* __restrict__ edge_order) {
    int e = blockIdx.x * blockDim.x + threadIdx.x;
    if (e >= NEDGES) return;
    int pos = atomicAdd(&cursor[receivers[e]], 1);
    edge_order[pos] = e;
}

// ---------------------------------------------------------------- permute edge data (once)
__global__ void perm_kernel(const int* __restrict__ edge_order,
                            const int* __restrict__ senders,
                            const float* __restrict__ nhat4,
                            float* __restrict__ nh_perm, int* __restrict__ snd_perm) {
    int i = blockIdx.x * blockDim.x + threadIdx.x;
    if (i >= NEDGES) return;
    int e = edge_order[i];
    *(float4*)(nh_perm + (size_t)i*4) = *(const float4*)(nhat4 + (size_t)e*4);
    snd_perm[i] = senders[e];
}

// ---------------------------------------------------------------- weight prep (once)
// w1t[l][k][b] from w_rad1[l][b][k]
// w3p[l][o][kp] = packed fp16 pair (w_rad_out[l][2kp][o], w_rad_out[l][2kp+1][o])
__global__ void prepw_kernel(const float* __restrict__ w1, const float* __restrict__ w3,
                             float* __restrict__ w1t, uint32* __restrict__ w3p) {
    int t = blockIdx.x * blockDim.x + threadIdx.x;
    if (t < NL * 64 * 8) {
        int l = t / 512, r = t % 512, k = r >> 3, b = r & 7;
        w1t[t] = w1[l * 512 + b * 64 + k];
    }
    int u = t - NL * 64 * 8;
    if (u >= 0 && u < NL * 160 * 32) {
        int l = u / 5120, r = u % 5120, o = r >> 5, kp = r & 31;
        const float* wl = w3 + l * 10240;
        w3p[u] = packh2(wl[(2*kp) * 160 + o], wl[(2*kp+1) * 160 + o]);
    }
}

// ---------------------------------------------------------------- node init
__global__ void init_kernel(const int* __restrict__ specie,
                            const float* __restrict__ emb,
                            float* __restrict__ s) {
    int t = blockIdx.x * blockDim.x + threadIdx.x;
    if (t >= NNODES * NC) return;
    int n = t >> 5;
    int c = t & 31;
    s[t] = emb[specie[n] * NC + c];
}

// ---------------------------------------------------------------- MLP stage A
// Thread-per-edge (receiver-sorted order i in [iBase, iBase+iCount)).
// rb -> h1 -> h2 (fp32, weights via wave-uniform s_load broadcast).
// Output: h2 packed as 32 fp16-pairs per edge (chunk-local index).
__global__ __launch_bounds__(256, 4) void mlpA_kernel(
    const float* __restrict__ rb,          // [E][8] original order
    const int* __restrict__ edge_order,    // [E]
    const float* __restrict__ w1t,         // [64][8]
    const float* __restrict__ w2,          // [64][64]
    uint32* __restrict__ h2p,              // [ECHUNK][32]
    int iBase, int iCount)
{
    int ii = blockIdx.x * 256 + threadIdx.x;
    if (ii >= iCount) return;
    int e = edge_order[iBase + ii];
    float4 ra = *(const float4*)(rb + (size_t)e * 8);
    float4 rv = *(const float4*)(rb + (size_t)e * 8 + 4);

    float acc[NH];
    #pragma unroll
    for (int j = 0; j < NH; ++j) acc[j] = 0.f;

    #pragma unroll 1
    for (int k = 0; k < NH; ++k) {
        const float* w1k = w1t + k * 8;
        float h;
        h = ra.x * w1k[0];
        h = fmaf(ra.y, w1k[1], h);
        h = fmaf(ra.z, w1k[2], h);
        h = fmaf(ra.w, w1k[3], h);
        h = fmaf(rv.x, w1k[4], h);
        h = fmaf(rv.y, w1k[5], h);
        h = fmaf(rv.z, w1k[6], h);
        h = fmaf(rv.w, w1k[7], h);
        h = silu_f(h);
        const float* w2k = w2 + k * NH;
        #pragma unroll
        for (int j = 0; j < NH; ++j) acc[j] = fmaf(h, w2k[j], acc[j]);
    }

    uint32* op = h2p + (size_t)ii * 32;
    #pragma unroll
    for (int q = 0; q < 8; ++q) {
        uint4 pk;
        pk.x = packh2(silu_f(acc[8*q+0]), silu_f(acc[8*q+1]));
        pk.y = packh2(silu_f(acc[8*q+2]), silu_f(acc[8*q+3]));
        pk.z = packh2(silu_f(acc[8*q+4]), silu_f(acc[8*q+5]));
        pk.w = packh2(silu_f(acc[8*q+6]), silu_f(acc[8*q+7]));
        *(uint4*)(op + 4*q) = pk;
    }
}

// ---------------------------------------------------------------- MLP stage B
// Thread-per-edge: wgt[160] = h2 @ W3 via v_dot2_f32_f16 (packed fp16 pairs).
// W3 pairs read wave-uniform -> s_load broadcast. Low VGPR -> 8 waves/SIMD.
__global__ __launch_bounds__(256, 8) void mlpB_kernel(
    const uint32* __restrict__ h2p,        // [ECHUNK][32]
    const uint32* __restrict__ w3p,        // [160][32]
    _Float16* __restrict__ wgt16,          // [E][160] permuted order
    int iBase, int iCount)
{
    int ii = blockIdx.x * 256 + threadIdx.x;
    if (ii >= iCount) return;

    uint32 h[32];
    const uint32* ip = h2p + (size_t)ii * 32;
    #pragma unroll
    for (int q = 0; q < 8; ++q) {
        uint4 v = *(const uint4*)(ip + 4*q);
        h[4*q+0] = v.x; h[4*q+1] = v.y; h[4*q+2] = v.z; h[4*q+3] = v.w;
    }

    _Float16* wp = wgt16 + (size_t)(iBase + ii) * 160;
    #pragma unroll 1
    for (int ob = 0; ob < 160; ob += 8) {
        float t[8];
        #pragma unroll
        for (int o = 0; o < 8; ++o) {
            const uint32* wr = w3p + (ob + o) * 32;
            float a = 0.f;
            #pragma unroll
            for (int kp = 0; kp < 32; ++kp)
                a = __builtin_amdgcn_fdot2(u2h(h[kp]), u2h(wr[kp]), a, false);
            t[o] = a;
        }
        uint4 pk;
        pk.x = packh2(t[0], t[1]);
        pk.y = packh2(t[2], t[3]);
        pk.z = packh2(t[4], t[5]);
        pk.w = packh2(t[6], t[7]);
        *(uint4*)(wp + ob) = pk;
    }
}

// ---------------------------------------------------------------- gather + TP
// One 64-lane wave per node; all edge data pre-permuted & coalesced. No LDS.
__global__ __launch_bounds__(512) void gather_tp_kernel(
    const _Float16* __restrict__ wgt16,   // [E][160]
    const float* __restrict__ nh_perm,    // [E][4]
    const int* __restrict__ snd_perm,     // [E]
    const int* __restrict__ rowstart, const int* __restrict__ deg,
    const float* __restrict__ s_in, const float* __restrict__ v_in,  // v: [N][3][32]
    float* __restrict__ agg_s,      // [N][64]
    float* __restrict__ agg_v)      // [N][96][3]
{
    int lane = threadIdx.x & 63;
    int wid  = threadIdx.x >> 6;
    int n = blockIdx.x * 8 + wid;
    if (n >= NNODES) return;

    int c = lane & 31;
    int half = lane >> 5;
    int off01 = half * 32 + c;

    float accS = 0.f;
    float aVa0 = 0.f, aVa1 = 0.f, aVa2 = 0.f;   // half0: path2, half1: path3
    float aVb0 = 0.f, aVb1 = 0.f, aVb2 = 0.f;   // half0: path4, half1: garbage

    int start = rowstart[n];
    int cnt   = deg[n];

    for (int i = 0; i < cnt; ++i) {
        int idx = start + i;
        float4 nh = *(const float4*)(nh_perm + (size_t)idx * 4);
        int snd = snd_perm[idx];
        const _Float16* wpt = wgt16 + (size_t)idx * 160;

        float d0  = (float)wpt[off01];        // half0: wgt0[c]  half1: wgt1[c]
        float d1  = (float)wpt[64 + off01];   // half0: wgt2[c]  half1: wgt3[c]
        float d2f = (float)wpt[128 + c];      // wgt4[c] (half1 discards)

        float su = s_in[(size_t)snd * NC + c];
        float v0 = v_in[(size_t)snd * 96 + c];
        float v1 = v_in[(size_t)snd * 96 + 32 + c];
        float v2 = v_in[(size_t)snd * 96 + 64 + c];
        float ndv = nh.x * v0;
        ndv = fmaf(nh.y, v1, ndv);
        ndv = fmaf(nh.z, v2, ndv);

        float sSel = half ? ndv : su;          // path1 vs path0 multiplier
        accS = fmaf(d0, sSel, accS);
        float scale = half ? d1 : d1 * su;     // path3: w3 ; path2: w2*su
        float f0 = half ? v0 : nh.x;
        float f1 = half ? v1 : nh.y;
        float f2 = half ? v2 : nh.z;
        aVa0 = fmaf(scale, f0, aVa0);
        aVa1 = fmaf(scale, f1, aVa1);
        aVa2 = fmaf(scale, f2, aVa2);
        float m4 = half ? 0.f : d2f;           // path4 only on half0
        aVb0 = fmaf(m4, fmaf(nh.x, ndv, -v0 * (1.f / 3.f)), aVb0);
        aVb1 = fmaf(m4, fmaf(nh.y, ndv, -v1 * (1.f / 3.f)), aVb1);
        aVb2 = fmaf(m4, fmaf(nh.z, ndv, -v2 * (1.f / 3.f)), aVb2);
    }

    agg_s[(size_t)n * 64 + lane] = accS;
    float* av = agg_v + (size_t)n * 288;
    if (half == 0) {
        av[c * 3 + 0] = aVa0; av[c * 3 + 1] = aVa1; av[c * 3 + 2] = aVa2;                      // path2
        av[(64 + c) * 3 + 0] = aVb0; av[(64 + c) * 3 + 1] = aVb1; av[(64 + c) * 3 + 2] = aVb2; // path4
    } else {
        av[(32 + c) * 3 + 0] = aVa0; av[(32 + c) * 3 + 1] = aVa1; av[(32 + c) * 3 + 2] = aVa2; // path3
    }
}

// ---------------------------------------------------------------- fallback gather (Round-2)
__global__ __launch_bounds__(512) void gather_kernel(
    const float* __restrict__ rb, const float* __restrict__ nhat4,
    const int* __restrict__ senders, const int* __restrict__ edge_order,
    const int* __restrict__ rowstart, const int* __restrict__ deg,
    const float* __restrict__ s_in, const float* __restrict__ v_in,
    const float* __restrict__ w1, const float* __restrict__ w2, const float* __restrict__ w3,
    float* __restrict__ agg_s, float* __restrict__ agg_v)
{
    __shared__ float sW2[NH * NH];
    __shared__ float sW3[NH * 160];
    for (int i = threadIdx.x; i < NH * NH;  i += 512) sW2[i] = w2[i];
    for (int i = threadIdx.x; i < NH * 160; i += 512) sW3[i] = w3[i];
    __syncthreads();
    int lane = threadIdx.x & 63;
    int wid  = threadIdx.x >> 6;
    int n = blockIdx.x * 8 + wid;
    if (n >= NNODES) return;
    int c = lane & 31;
    int half = lane >> 5;
    float w1r[8];
    #pragma unroll
    for (int b = 0; b < 8; ++b) w1r[b] = w1[b * NH + lane];
    float accS = 0.f;
    float aVa0 = 0.f, aVa1 = 0.f, aVa2 = 0.f;
    float aVb0 = 0.f, aVb1 = 0.f, aVb2 = 0.f;
    int start = rowstart[n];
    int cnt   = deg[n];
    for (int i = 0; i < cnt; ++i) {
        int e   = edge_order[start + i];
        int snd = senders[e];
        float4 nh  = *(const float4*)(nhat4 + (size_t)e * 4);
        float4 rba = *(const float4*)(rb + (size_t)e * 8);
        float4 rbb = *(const float4*)(rb + (size_t)e * 8 + 4);
        float h1v;
        h1v = rba.x * w1r[0];
        h1v = fmaf(rba.y, w1r[1], h1v);
        h1v = fmaf(rba.z, w1r[2], h1v);
        h1v = fmaf(rba.w, w1r[3], h1v);
        h1v = fmaf(rbb.x, w1r[4], h1v);
        h1v = fmaf(rbb.y, w1r[5], h1v);
        h1v = fmaf(rbb.z, w1r[6], h1v);
        h1v = fmaf(rbb.w, w1r[7], h1v);
        h1v = silu_f(h1v);
        float a0 = 0.f, a1 = 0.f;
        #pragma unroll
        for (int k = 0; k < NH; k += 2) {
            a0 = fmaf(__uint_as_float(__builtin_amdgcn_readlane(__float_as_uint(h1v), k)),     sW2[k * NH + lane],       a0);
            a1 = fmaf(__uint_as_float(__builtin_amdgcn_readlane(__float_as_uint(h1v), k + 1)), sW2[(k + 1) * NH + lane], a1);
        }
        float h2v = silu_f(a0 + a1);
        float d0a = 0.f, d0b = 0.f, d1a = 0.f, d1b = 0.f, d2a = 0.f, d2b = 0.f;
        #pragma unroll
        for (int k = 0; k < NH; k += 2) {
            float hA = __uint_as_float(__builtin_amdgcn_readlane(__float_as_uint(h2v), k));
            float hB = __uint_as_float(__builtin_amdgcn_readlane(__float_as_uint(h2v), k + 1));
            d0a = fmaf(hA, sW3[k * 160 + lane],            d0a);
            d1a = fmaf(hA, sW3[k * 160 + 64 + lane],       d1a);
            d2a = fmaf(hA, sW3[k * 160 + 128 + c],         d2a);
            d0b = fmaf(hB, sW3[(k + 1) * 160 + lane],      d0b);
            d1b = fmaf(hB, sW3[(k + 1) * 160 + 64 + lane], d1b);
            d2b = fmaf(hB, sW3[(k + 1) * 160 + 128 + c],   d2b);
        }
        float d0 = d0a + d0b;
        float d1 = d1a + d1b;
        float d2 = d2a + d2b;
        float su = s_in[(size_t)snd * NC + c];
        float v0 = v_in[(size_t)snd * 96 + c];
        float v1 = v_in[(size_t)snd * 96 + 32 + c];
        float v2 = v_in[(size_t)snd * 96 + 64 + c];
        float ndv = nh.x * v0;
        ndv = fmaf(nh.y, v1, ndv);
        ndv = fmaf(nh.z, v2, ndv);
        float sSel = half ? ndv : su;
        accS = fmaf(d0, sSel, accS);
        float scale = half ? d1 : d1 * su;
        float f0 = half ? v0 : nh.x;
        float f1 = half ? v1 : nh.y;
        float f2 = half ? v2 : nh.z;
        aVa0 = fmaf(scale, f0, aVa0);
        aVa1 = fmaf(scale, f1, aVa1);
        aVa2 = fmaf(scale, f2, aVa2);
        float m4 = half ? 0.f : d2;
        aVb0 = fmaf(m4, fmaf(nh.x, ndv, -v0 * (1.f / 3.f)), aVb0);
        aVb1 = fmaf(m4, fmaf(nh.y, ndv, -v1 * (1.f / 3.f)), aVb1);
        aVb2 = fmaf(m4, fmaf(nh.z, ndv, -v2 * (1.f / 3.f)), aVb2);
    }
    agg_s[(size_t)n * 64 + lane] = accS;
    float* av = agg_v + (size_t)n * 288;
    if (half == 0) {
        av[c * 3 + 0] = aVa0; av[c * 3 + 1] = aVa1; av[c * 3 + 2] = aVa2;
        av[(64 + c) * 3 + 0] = aVb0; av[(64 + c) * 3 + 1] = aVb1; av[(64 + c) * 3 + 2] = aVb2;
    } else {
        av[(32 + c) * 3 + 0] = aVa0; av[(32 + c) * 3 + 1] = aVa1; av[(32 + c) * 3 + 2] = aVa2;
    }
}

// ---------------------------------------------------------------- node update
__global__ __launch_bounds__(256) void node_kernel(
    const int* __restrict__ specie,
    const float* __restrict__ agg_s, const float* __restrict__ agg_v,
    const float* __restrict__ s_in,  const float* __restrict__ v_in,
    const float* __restrict__ wls,   // [64][64]
    const float* __restrict__ wlv,   // [96][32]
    const float* __restrict__ wscs,  // [5][32][64]
    const float* __restrict__ wscv,  // [5][32][32]
    float* __restrict__ s_out, float* __restrict__ v_out)
{
    int t = blockIdx.x * blockDim.x + threadIdx.x;
    int n = t >> 6;
    int k = t & 63;
    if (n >= NNODES) return;
    int sp = specie[n];

    const float* as   = agg_s + (size_t)n * 64;
    const float* sold = s_in  + (size_t)n * NC;

    float sg = 0.f;
    #pragma unroll 1
    for (int j = 0; j < 64; ++j) sg += as[j] * wls[j * 64 + k];
    sg *= INV_AVG;
    const float* ws = wscs + (size_t)sp * NC * 64;
    #pragma unroll 1
    for (int j = 0; j < NC; ++j) sg += sold[j] * ws[j * 64 + k];

    float act = silu_f(sg);
    float gate = __shfl(act, (k & 31) + 32);   // gate for channel (k&31)

    if (k < NC) {
        int c = k;
        const float* av = agg_v + (size_t)n * 288;
        float vn0 = 0.f, vn1 = 0.f, vn2 = 0.f;
        #pragma unroll 1
        for (int p = 0; p < 96; ++p) {
            float w = wlv[p * NC + c];
            vn0 += av[3*p+0] * w;
            vn1 += av[3*p+1] * w;
            vn2 += av[3*p+2] * w;
        }
        vn0 *= INV_AVG; vn1 *= INV_AVG; vn2 *= INV_AVG;
        const float* wv   = wscv + (size_t)sp * NC * NC;
        const float* vold = v_in + (size_t)n * 96;
        #pragma unroll 1
        for (int j = 0; j < NC; ++j) {
            float w = wv[j * NC + c];
            vn0 += vold[j]      * w;
            vn1 += vold[32 + j] * w;
            vn2 += vold[64 + j] * w;
        }
        s_out[(size_t)n * NC + c] = act;
        v_out[(size_t)n * 96 + c]      = gate * vn0;
        v_out[(size_t)n * 96 + 32 + c] = gate * vn1;
        v_out[(size_t)n * 96 + 64 + c] = gate * vn2;
    }
}

// ---------------------------------------------------------------- output head
__global__ void out_kernel(const float* __restrict__ s,
                           const float* __restrict__ w1,  // [32][16]
                           const float* __restrict__ w2,  // [16][1]
                           float* __restrict__ out) {
    int n = blockIdx.x * blockDim.x + threadIdx.x;
    if (n >= NNODES) return;
    float sv[NC];
    #pragma unroll
    for (int c = 0; c < NC; ++c) sv[c] = s[(size_t)n * NC + c];
    float e = 0.f;
    #pragma unroll
    for (int j = 0; j < 16; ++j) {
        float tj = 0.f;
        #pragma unroll
        for (int c = 0; c < NC; ++c) tj += sv[c] * w1[c * 16 + j];
        e += tj * w2[j];
    }
    out[n] = e;
}

// ---------------------------------------------------------------- launcher
extern "C" void kernel_launch(void* const* d_in, const int* in_sizes, int n_in,
                              void* d_out, int out_size, void* d_ws, size_t ws_size,
                              hipStream_t stream) {
    const float* vectors   = (const float*)d_in[0];
    const int*   specie    = (const int*)  d_in[1];
    const int*   senders   = (const int*)  d_in[2];
    const int*   receivers = (const int*)  d_in[3];
    const float* emb       = (const float*)d_in[4];
    const float* w_rad1    = (const float*)d_in[5];
    const float* w_rad2    = (const float*)d_in[6];
    const float* w_rad_out = (const float*)d_in[7];
    const float* w_lin_s   = (const float*)d_in[8];
    const float* w_lin_v   = (const float*)d_in[9];
    const float* w_sc_s    = (const float*)d_in[10];
    const float* w_sc_v    = (const float*)d_in[11];
    const float* w_out1    = (const float*)d_in[12];
    const float* w_out2    = (const float*)d_in[13];

    char* base = (char*)d_ws;
    size_t off = 0;
    auto alloc = [&](size_t bytes) { char* q = base + off; off += (bytes + 255) & ~(size_t)255; return q; };

    float* nhat4 = (float*)alloc((size_t)NEDGES * 4 * 4);
    float* rb    = (float*)alloc((size_t)NEDGES * 8 * 4);
    float* s_a   = (float*)alloc((size_t)NNODES * NC * 4);
    float* v_a   = (float*)alloc((size_t)NNODES * NC * 3 * 4);
    float* s_b   = (float*)alloc((size_t)NNODES * NC * 4);
    float* v_b   = (float*)alloc((size_t)NNODES * NC * 3 * 4);
    float* aggs  = (float*)alloc((size_t)NNODES * 2 * NC * 4);
    float* aggv  = (float*)alloc((size_t)NNODES * 3 * NC * 3 * 4);  // 34.56 MB; h2p aliases this
    int* deg        = (int*)alloc((size_t)NNODES * 4);
    int* rowstart   = (int*)alloc((size_t)(NNODES + 4) * 4);
    int* cursor     = (int*)alloc((size_t)NNODES * 4);
    int* edge_order = (int*)alloc((size_t)NEDGES * 4);
    // big-path extras
    float*    nh_perm  = (float*)alloc((size_t)NEDGES * 4 * 4);
    int*      snd_perm = (int*)alloc((size_t)NEDGES * 4);
    float*    w1t      = (float*)alloc((size_t)NL * 64 * 8 * 4);
    uint32*   w3p      = (uint32*)alloc((size_t)NL * 160 * 32 * 4);
    _Float16* wgt16    = (_Float16*)alloc((size_t)NEDGES * 160 * 2);
    bool big = (off <= ws_size);

    // h2p aliases aggv: lifetime is within-layer {mlpA, mlpB} which completes
    // before gather_tp writes aggs/aggv. ECHUNK*32*4 = 30.72 MB <= 34.56 MB.
    uint32* h2p = (uint32*)aggv;

    // geometry + CSR (once; graph static across layers)
    geom_kernel<<<(NEDGES + 255) / 256, 256, 0, stream>>>(vectors, nhat4, rb);
    (void)hipMemsetAsync(deg, 0, NNODES * sizeof(int), stream);
    count_kernel<<<(NEDGES + 255) / 256, 256, 0, stream>>>(receivers, deg);
    scan_kernel<<<1, 256, 0, stream>>>(deg, rowstart);
    copy_cursor_kernel<<<(NNODES + 255) / 256, 256, 0, stream>>>(rowstart, cursor);
    fill_kernel<<<(NEDGES + 255) / 256, 256, 0, stream>>>(receivers, cursor, edge_order);
    if (big) {
        perm_kernel<<<(NEDGES + 255) / 256, 256, 0, stream>>>(edge_order, senders, nhat4, nh_perm, snd_perm);
        prepw_kernel<<<(NL * (64 * 8 + 160 * 32) + 255) / 256, 256, 0, stream>>>(w_rad1, w_rad_out, w1t, w3p);
    }

    init_kernel<<<(NNODES * NC + 255) / 256, 256, 0, stream>>>(specie, emb, s_a);
    (void)hipMemsetAsync(v_a, 0, (size_t)NNODES * NC * 3 * sizeof(float), stream);

    float* si = s_a; float* vi = v_a; float* so = s_b; float* vo = v_b;
    for (int l = 0; l < NL; ++l) {
        if (big) {
            for (int ch = 0; ch < 2; ++ch) {
                int iBase = ch * ECHUNK;
                mlpA_kernel<<<(ECHUNK + 255) / 256, 256, 0, stream>>>(
                    rb, edge_order,
                    w1t + (size_t)l * 64 * 8,
                    w_rad2 + (size_t)l * NH * NH,
                    h2p, iBase, ECHUNK);
                mlpB_kernel<<<(ECHUNK + 255) / 256, 256, 0, stream>>>(
                    h2p, w3p + (size_t)l * 160 * 32, wgt16, iBase, ECHUNK);
            }
            gather_tp_kernel<<<NNODES / 8, 512, 0, stream>>>(
                wgt16, nh_perm, snd_perm, rowstart, deg, si, vi, aggs, aggv);
        } else {
            gather_kernel<<<NNODES / 8, 512, 0, stream>>>(
                rb, nhat4, senders, edge_order, rowstart, deg, si, vi,
                w_rad1 + (size_t)l * NBASIS * NH,
                w_rad2 + (size_t)l * NH * NH,
                w_rad_out + (size_t)l * NH * 160,
                aggs, aggv);
        }
        node_kernel<<<(NNODES * 64 + 255) / 256, 256, 0, stream>>>(
            specie, aggs, aggv, si, vi,
            w_lin_s + (size_t)l * 64 * 64,
            w_lin_v + (size_t)l * 96 * 32,
            w_sc_s + (size_t)l * NSPEC * NC * 64,
            w_sc_v + (size_t)l * NSPEC * NC * NC,
            so, vo);
        float* ts = si; si = so; so = ts;
        float* tv = vi; vi = vo; vo = tv;
    }

    out_kernel<<<(NNODES + 255) / 256, 256, 0, stream>>>(si, w_out1, w_out2, (float*)d_out);
}

// Round 8
// 1277.692 us; speedup vs baseline: 20.5242x; 1.3845x over previous
//
#include <hip/hip_runtime.h>
#include <math.h>

#define NNODES 30000
#define NEDGES 480000
#define NC 32
#define NL 3
#define NH 64
#define NBASIS 8
#define NSPEC 5
#define INV_AVG 0.0625f   // 1 / AVG_NEIGH
#define ECHUNK 240000     // NEDGES/2 — h2p chunk (aliases aggv)

typedef _Float16 half2v __attribute__((ext_vector_type(2)));
typedef unsigned int uint32;

__device__ __forceinline__ float silu_f(float x) {
    return x / (1.f + __expf(-x));
}
__device__ __forceinline__ float rdlane(float v, int k) {
    return __uint_as_float(__builtin_amdgcn_readlane(__float_as_uint(v), k));
}
__device__ __forceinline__ half2v u2h(uint32 u) {
    union { uint32 u; half2v h; } x; x.u = u; return x.h;
}
__device__ __forceinline__ uint32 packh2(float a, float b) {
    union { uint32 u; half2v h; } x;
    x.h.x = (_Float16)a; x.h.y = (_Float16)b; return x.u;
}

// ---------------------------------------------------------------- geometry
__global__ void geom_kernel(const float* __restrict__ vec,
                            float* __restrict__ nhat4,   // [E][4]
                            float* __restrict__ rb) {    // [E][8]
    int e = blockIdx.x * blockDim.x + threadIdx.x;
    if (e >= NEDGES) return;
    float vx = vec[3*e+0] * 0.25f;   // vectors / R_MAX
    float vy = vec[3*e+1] * 0.25f;
    float vz = vec[3*e+2] * 0.25f;
    float len = sqrtf(vx*vx + vy*vy + vz*vz);      // scaled length
    float inv = 1.f / fmaxf(len, 1e-9f);
    float4 nh = make_float4(vx*inv, vy*inv, vz*inv, 0.f);
    *(float4*)(nhat4 + (size_t)e*4) = nh;
    float x = len * 0.25f;                         // lengths / R_MAX (again)
    float x3 = x*x*x;
    float x6 = x3*x3;
    float x7 = x6*x;
    float x8 = x7*x;
    float env = (x < 1.f) ? (1.f - 28.f*x6 + 48.f*x7 - 21.f*x8) : 0.f;
    float scale = 0.7071067811865476f * inv * env; // sqrt(2/R_MAX)/max(len,eps)*env
    #pragma unroll
    for (int i = 0; i < NBASIS; ++i) {
        rb[NBASIS*e + i] = scale * sinf((float)(i+1) * 3.14159265358979f * x);
    }
}

// ---------------------------------------------------------------- CSR build
__global__ void count_kernel(const int* __restrict__ receivers, int* __restrict__ deg) {
    int e = blockIdx.x * blockDim.x + threadIdx.x;
    if (e >= NEDGES) return;
    atomicAdd(&deg[receivers[e]], 1);
}

__global__ void scan_kernel(const int* __restrict__ deg, int* __restrict__ rowstart) {
    __shared__ int lsum[256];
    __shared__ int loff[256];
    int t = threadIdx.x;
    int lo = t * 118;
    int hi = min(lo + 118, NNODES);
    int s = 0;
    for (int i = lo; i < hi; ++i) s += deg[i];
    lsum[t] = s;
    __syncthreads();
    if (t == 0) {
        int run = 0;
        for (int i = 0; i < 256; ++i) { loff[i] = run; run += lsum[i]; }
    }
    __syncthreads();
    int run = loff[t];
    for (int i = lo; i < hi; ++i) { rowstart[i] = run; run += deg[i]; }
    if (t == 0) rowstart[NNODES] = NEDGES;
}

__global__ void copy_cursor_kernel(const int* __restrict__ rowstart, int* __restrict__ cursor) {
    int i = blockIdx.x * blockDim.x + threadIdx.x;
    if (i < NNODES) cursor[i] = rowstart[i];
}

__global__ void fill_kernel(const int* __restrict__ receivers,
                            int* __restrict__ cursor, int* __restrict__ edge_order) {
    int e = blockIdx.x * blockDim.x + threadIdx.x;
    if (e >= NEDGES) return;
    int pos = atomicAdd(&cursor[receivers[e]], 1);
    edge_order[pos] = e;
}

// ---------------------------------------------------------------- permute edge data (once)
__global__ void perm_kernel(const int* __restrict__ edge_order,
                            const int* __restrict__ senders,
                            const float* __restrict__ nhat4,
                            float* __restrict__ nh_perm, int* __restrict__ snd_perm) {
    int i = blockIdx.x * blockDim.x + threadIdx.x;
    if (i >= NEDGES) return;
    int e = edge_order[i];
    *(float4*)(nh_perm + (size_t)i*4) = *(const float4*)(nhat4 + (size_t)e*4);
    snd_perm[i] = senders[e];
}

// ---------------------------------------------------------------- weight prep (once)
// w1t[l][k][b] from w_rad1[l][b][k]
// w3p[l][o][kp] = packed fp16 pair (w_rad_out[l][2kp][o], w_rad_out[l][2kp+1][o])
__global__ void prepw_kernel(const float* __restrict__ w1, const float* __restrict__ w3,
                             float* __restrict__ w1t, uint32* __restrict__ w3p) {
    int t = blockIdx.x * blockDim.x + threadIdx.x;
    if (t < NL * 64 * 8) {
        int l = t / 512, r = t % 512, k = r >> 3, b = r & 7;
        w1t[t] = w1[l * 512 + b * 64 + k];
    }
    int u = t - NL * 64 * 8;
    if (u >= 0 && u < NL * 160 * 32) {
        int l = u / 5120, r = u % 5120, o = r >> 5, kp = r & 31;
        const float* wl = w3 + l * 10240;
        w3p[u] = packh2(wl[(2*kp) * 160 + o], wl[(2*kp+1) * 160 + o]);
    }
}

// ---------------------------------------------------------------- node init
__global__ void init_kernel(const int* __restrict__ specie,
                            const float* __restrict__ emb,
                            float* __restrict__ s) {
    int t = blockIdx.x * blockDim.x + threadIdx.x;
    if (t >= NNODES * NC) return;
    int n = t >> 5;
    int c = t & 31;
    s[t] = emb[specie[n] * NC + c];
}

// ---------------------------------------------------------------- MLP stage A
__global__ __launch_bounds__(256, 4) void mlpA_kernel(
    const float* __restrict__ rb,          // [E][8] original order
    const int* __restrict__ edge_order,    // [E]
    const float* __restrict__ w1t,         // [64][8]
    const float* __restrict__ w2,          // [64][64]
    uint32* __restrict__ h2p,              // [ECHUNK][32]
    int iBase, int iCount)
{
    int ii = blockIdx.x * 256 + threadIdx.x;
    if (ii >= iCount) return;
    int e = edge_order[iBase + ii];
    float4 ra = *(const float4*)(rb + (size_t)e * 8);
    float4 rv = *(const float4*)(rb + (size_t)e * 8 + 4);

    float acc[NH];
    #pragma unroll
    for (int j = 0; j < NH; ++j) acc[j] = 0.f;

    #pragma unroll 1
    for (int k = 0; k < NH; ++k) {
        const float* w1k = w1t + k * 8;
        float h;
        h = ra.x * w1k[0];
        h = fmaf(ra.y, w1k[1], h);
        h = fmaf(ra.z, w1k[2], h);
        h = fmaf(ra.w, w1k[3], h);
        h = fmaf(rv.x, w1k[4], h);
        h = fmaf(rv.y, w1k[5], h);
        h = fmaf(rv.z, w1k[6], h);
        h = fmaf(rv.w, w1k[7], h);
        h = silu_f(h);
        const float* w2k = w2 + k * NH;
        #pragma unroll
        for (int j = 0; j < NH; ++j) acc[j] = fmaf(h, w2k[j], acc[j]);
    }

    uint32* op = h2p + (size_t)ii * 32;
    #pragma unroll
    for (int q = 0; q < 8; ++q) {
        uint4 pk;
        pk.x = packh2(silu_f(acc[8*q+0]), silu_f(acc[8*q+1]));
        pk.y = packh2(silu_f(acc[8*q+2]), silu_f(acc[8*q+3]));
        pk.z = packh2(silu_f(acc[8*q+4]), silu_f(acc[8*q+5]));
        pk.w = packh2(silu_f(acc[8*q+6]), silu_f(acc[8*q+7]));
        *(uint4*)(op + 4*q) = pk;
    }
}

// ---------------------------------------------------------------- MLP stage B
__global__ __launch_bounds__(256, 8) void mlpB_kernel(
    const uint32* __restrict__ h2p,        // [ECHUNK][32]
    const uint32* __restrict__ w3p,        // [160][32]
    _Float16* __restrict__ wgt16,          // [E][160] permuted order
    int iBase, int iCount)
{
    int ii = blockIdx.x * 256 + threadIdx.x;
    if (ii >= iCount) return;

    uint32 h[32];
    const uint32* ip = h2p + (size_t)ii * 32;
    #pragma unroll
    for (int q = 0; q < 8; ++q) {
        uint4 v = *(const uint4*)(ip + 4*q);
        h[4*q+0] = v.x; h[4*q+1] = v.y; h[4*q+2] = v.z; h[4*q+3] = v.w;
    }

    _Float16* wp = wgt16 + (size_t)(iBase + ii) * 160;
    #pragma unroll 1
    for (int ob = 0; ob < 160; ob += 8) {
        float t[8];
        #pragma unroll
        for (int o = 0; o < 8; ++o) {
            const uint32* wr = w3p + (ob + o) * 32;
            float a = 0.f;
            #pragma unroll
            for (int kp = 0; kp < 32; ++kp)
                a = __builtin_amdgcn_fdot2(u2h(h[kp]), u2h(wr[kp]), a, false);
            t[o] = a;
        }
        uint4 pk;
        pk.x = packh2(t[0], t[1]);
        pk.y = packh2(t[2], t[3]);
        pk.z = packh2(t[4], t[5]);
        pk.w = packh2(t[6], t[7]);
        *(uint4*)(wp + ob) = pk;
    }
}

// ---------------------------------------------------------------- gather + TP
__global__ __launch_bounds__(512) void gather_tp_kernel(
    const _Float16* __restrict__ wgt16,   // [E][160]
    const float* __restrict__ nh_perm,    // [E][4]
    const int* __restrict__ snd_perm,     // [E]
    const int* __restrict__ rowstart, const int* __restrict__ deg,
    const float* __restrict__ s_in, const float* __restrict__ v_in,  // v: [N][3][32]
    float* __restrict__ agg_s,      // [N][64]
    float* __restrict__ agg_v)      // [N][96][3]
{
    int lane = threadIdx.x & 63;
    int wid  = threadIdx.x >> 6;
    int n = blockIdx.x * 8 + wid;
    if (n >= NNODES) return;

    int c = lane & 31;
    int half = lane >> 5;
    int off01 = half * 32 + c;

    float accS = 0.f;
    float aVa0 = 0.f, aVa1 = 0.f, aVa2 = 0.f;   // half0: path2, half1: path3
    float aVb0 = 0.f, aVb1 = 0.f, aVb2 = 0.f;   // half0: path4, half1: garbage

    int start = rowstart[n];
    int cnt   = deg[n];

    for (int i = 0; i < cnt; ++i) {
        int idx = start + i;
        float4 nh = *(const float4*)(nh_perm + (size_t)idx * 4);
        int snd = snd_perm[idx];
        const _Float16* wpt = wgt16 + (size_t)idx * 160;

        float d0  = (float)wpt[off01];        // half0: wgt0[c]  half1: wgt1[c]
        float d1  = (float)wpt[64 + off01];   // half0: wgt2[c]  half1: wgt3[c]
        float d2f = (float)wpt[128 + c];      // wgt4[c] (half1 discards)

        float su = s_in[(size_t)snd * NC + c];
        float v0 = v_in[(size_t)snd * 96 + c];
        float v1 = v_in[(size_t)snd * 96 + 32 + c];
        float v2 = v_in[(size_t)snd * 96 + 64 + c];
        float ndv = nh.x * v0;
        ndv = fmaf(nh.y, v1, ndv);
        ndv = fmaf(nh.z, v2, ndv);

        float sSel = half ? ndv : su;          // path1 vs path0 multiplier
        accS = fmaf(d0, sSel, accS);
        float scale = half ? d1 : d1 * su;     // path3: w3 ; path2: w2*su
        float f0 = half ? v0 : nh.x;
        float f1 = half ? v1 : nh.y;
        float f2 = half ? v2 : nh.z;
        aVa0 = fmaf(scale, f0, aVa0);
        aVa1 = fmaf(scale, f1, aVa1);
        aVa2 = fmaf(scale, f2, aVa2);
        float m4 = half ? 0.f : d2f;           // path4 only on half0
        aVb0 = fmaf(m4, fmaf(nh.x, ndv, -v0 * (1.f / 3.f)), aVb0);
        aVb1 = fmaf(m4, fmaf(nh.y, ndv, -v1 * (1.f / 3.f)), aVb1);
        aVb2 = fmaf(m4, fmaf(nh.z, ndv, -v2 * (1.f / 3.f)), aVb2);
    }

    agg_s[(size_t)n * 64 + lane] = accS;
    float* av = agg_v + (size_t)n * 288;
    if (half == 0) {
        av[c * 3 + 0] = aVa0; av[c * 3 + 1] = aVa1; av[c * 3 + 2] = aVa2;                      // path2
        av[(64 + c) * 3 + 0] = aVb0; av[(64 + c) * 3 + 1] = aVb1; av[(64 + c) * 3 + 2] = aVb2; // path4
    } else {
        av[(32 + c) * 3 + 0] = aVa0; av[(32 + c) * 3 + 1] = aVa1; av[(32 + c) * 3 + 2] = aVa2; // path3
    }
}

// ---------------------------------------------------------------- fallback gather (Round-2)
__global__ __launch_bounds__(512) void gather_kernel(
    const float* __restrict__ rb, const float* __restrict__ nhat4,
    const int* __restrict__ senders, const int* __restrict__ edge_order,
    const int* __restrict__ rowstart, const int* __restrict__ deg,
    const float* __restrict__ s_in, const float* __restrict__ v_in,
    const float* __restrict__ w1, const float* __restrict__ w2, const float* __restrict__ w3,
    float* __restrict__ agg_s, float* __restrict__ agg_v)
{
    __shared__ float sW2[NH * NH];
    __shared__ float sW3[NH * 160];
    for (int i = threadIdx.x; i < NH * NH;  i += 512) sW2[i] = w2[i];
    for (int i = threadIdx.x; i < NH * 160; i += 512) sW3[i] = w3[i];
    __syncthreads();
    int lane = threadIdx.x & 63;
    int wid  = threadIdx.x >> 6;
    int n = blockIdx.x * 8 + wid;
    if (n >= NNODES) return;
    int c = lane & 31;
    int half = lane >> 5;
    float w1r[8];
    #pragma unroll
    for (int b = 0; b < 8; ++b) w1r[b] = w1[b * NH + lane];
    float accS = 0.f;
    float aVa0 = 0.f, aVa1 = 0.f, aVa2 = 0.f;
    float aVb0 = 0.f, aVb1 = 0.f, aVb2 = 0.f;
    int start = rowstart[n];
    int cnt   = deg[n];
    for (int i = 0; i < cnt; ++i) {
        int e   = edge_order[start + i];
        int snd = senders[e];
        float4 nh  = *(const float4*)(nhat4 + (size_t)e * 4);
        float4 rba = *(const float4*)(rb + (size_t)e * 8);
        float4 rbb = *(const float4*)(rb + (size_t)e * 8 + 4);
        float h1v;
        h1v = rba.x * w1r[0];
        h1v = fmaf(rba.y, w1r[1], h1v);
        h1v = fmaf(rba.z, w1r[2], h1v);
        h1v = fmaf(rba.w, w1r[3], h1v);
        h1v = fmaf(rbb.x, w1r[4], h1v);
        h1v = fmaf(rbb.y, w1r[5], h1v);
        h1v = fmaf(rbb.z, w1r[6], h1v);
        h1v = fmaf(rbb.w, w1r[7], h1v);
        h1v = silu_f(h1v);
        float a0 = 0.f, a1 = 0.f;
        #pragma unroll
        for (int k = 0; k < NH; k += 2) {
            a0 = fmaf(rdlane(h1v, k),     sW2[k * NH + lane],       a0);
            a1 = fmaf(rdlane(h1v, k + 1), sW2[(k + 1) * NH + lane], a1);
        }
        float h2v = silu_f(a0 + a1);
        float d0a = 0.f, d0b = 0.f, d1a = 0.f, d1b = 0.f, d2a = 0.f, d2b = 0.f;
        #pragma unroll
        for (int k = 0; k < NH; k += 2) {
            float hA = rdlane(h2v, k);
            float hB = rdlane(h2v, k + 1);
            d0a = fmaf(hA, sW3[k * 160 + lane],            d0a);
            d1a = fmaf(hA, sW3[k * 160 + 64 + lane],       d1a);
            d2a = fmaf(hA, sW3[k * 160 + 128 + c],         d2a);
            d0b = fmaf(hB, sW3[(k + 1) * 160 + lane],      d0b);
            d1b = fmaf(hB, sW3[(k + 1) * 160 + 64 + lane], d1b);
            d2b = fmaf(hB, sW3[(k + 1) * 160 + 128 + c],   d2b);
        }
        float d0 = d0a + d0b;
        float d1 = d1a + d1b;
        float d2 = d2a + d2b;
        float su = s_in[(size_t)snd * NC + c];
        float v0 = v_in[(size_t)snd * 96 + c];
        float v1 = v_in[(size_t)snd * 96 + 32 + c];
        float v2 = v_in[(size_t)snd * 96 + 64 + c];
        float ndv = nh.x * v0;
        ndv = fmaf(nh.y, v1, ndv);
        ndv = fmaf(nh.z, v2, ndv);
        float sSel = half ? ndv : su;
        accS = fmaf(d0, sSel, accS);
        float scale = half ? d1 : d1 * su;
        float f0 = half ? v0 : nh.x;
        float f1 = half ? v1 : nh.y;
        float f2 = half ? v2 : nh.z;
        aVa0 = fmaf(scale, f0, aVa0);
        aVa1 = fmaf(scale, f1, aVa1);
        aVa2 = fmaf(scale, f2, aVa2);
        float m4 = half ? 0.f : d2;
        aVb0 = fmaf(m4, fmaf(nh.x, ndv, -v0 * (1.f / 3.f)), aVb0);
        aVb1 = fmaf(m4, fmaf(nh.y, ndv, -v1 * (1.f / 3.f)), aVb1);
        aVb2 = fmaf(m4, fmaf(nh.z, ndv, -v2 * (1.f / 3.f)), aVb2);
    }
    agg_s[(size_t)n * 64 + lane] = accS;
    float* av = agg_v + (size_t)n * 288;
    if (half == 0) {
        av[c * 3 + 0] = aVa0; av[c * 3 + 1] = aVa1; av[c * 3 + 2] = aVa2;
        av[(64 + c) * 3 + 0] = aVb0; av[(64 + c) * 3 + 1] = aVb1; av[(64 + c) * 3 + 2] = aVb2;
    } else {
        av[(32 + c) * 3 + 0] = aVa0; av[(32 + c) * 3 + 1] = aVa1; av[(32 + c) * 3 + 2] = aVa2;
    }
}

// ---------------------------------------------------------------- node update (v2)
// One 64-lane wave per node (block = 4 nodes). Scalar part: readlane broadcast
// of per-lane-loaded agg_s/s_old + coalesced weight rows (L1-resident), fully
// unrolled -> pipelined loads, no serial scalar chains. Vector part: stage
// agg_v (288 f) + v_old (96 f) in LDS; lane (half=d, c) computes vn[d][c] and
// vn[2][c] via broadcast LDS reads (<=2 distinct addrs -> conflict-free).
__global__ __launch_bounds__(256) void node_kernel(
    const int* __restrict__ specie,
    const float* __restrict__ agg_s, const float* __restrict__ agg_v,
    const float* __restrict__ s_in,  const float* __restrict__ v_in,
    const float* __restrict__ wls,   // [64][64]
    const float* __restrict__ wlv,   // [96][32]
    const float* __restrict__ wscs,  // [5][32][64]
    const float* __restrict__ wscv,  // [5][32][32]
    float* __restrict__ s_out, float* __restrict__ v_out)
{
    __shared__ float sAV[4][288];
    __shared__ float sVO[4][96];

    int lane = threadIdx.x & 63;
    int wid  = threadIdx.x >> 6;
    int n = blockIdx.x * 4 + wid;
    if (n >= NNODES) return;
    int sp = specie[n];

    // stage agg_v and v_old into LDS (coalesced loads)
    const float* av = agg_v + (size_t)n * 288;
    sAV[wid][lane]       = av[lane];
    sAV[wid][64 + lane]  = av[64 + lane];
    sAV[wid][128 + lane] = av[128 + lane];
    sAV[wid][192 + lane] = av[192 + lane];
    if (lane < 32) sAV[wid][256 + lane] = av[256 + lane];
    const float* vo = v_in + (size_t)n * 96;
    if (lane < 32) {
        sVO[wid][lane]      = vo[lane];
        sVO[wid][32 + lane] = vo[32 + lane];
        sVO[wid][64 + lane] = vo[64 + lane];
    }

    float asv = agg_s[(size_t)n * 64 + lane];
    float sv  = s_in[(size_t)n * 32 + (lane & 31)];

    __syncthreads();

    // scalar part: sg[k=lane]
    float sg = 0.f;
    #pragma unroll
    for (int j = 0; j < 64; ++j)
        sg = fmaf(rdlane(asv, j), wls[j * 64 + lane], sg);
    sg *= INV_AVG;
    const float* ws = wscs + (size_t)sp * 32 * 64;
    #pragma unroll
    for (int j = 0; j < 32; ++j)
        sg = fmaf(rdlane(sv, j), ws[j * 64 + lane], sg);
    float act  = silu_f(sg);
    float gate = __shfl(act, (lane & 31) + 32);

    // vector part: lane (h, c) -> vn[h][c]; h==0 additionally vn[2][c]
    int c = lane & 31;
    int h = lane >> 5;
    float vn1 = 0.f, vn2 = 0.f;
    #pragma unroll
    for (int p = 0; p < 96; ++p) {
        float w = wlv[p * 32 + c];
        vn1 = fmaf(sAV[wid][3 * p + h], w, vn1);
        vn2 = fmaf(sAV[wid][3 * p + 2], w, vn2);
    }
    vn1 *= INV_AVG; vn2 *= INV_AVG;
    const float* wv = wscv + (size_t)sp * 32 * 32;
    #pragma unroll
    for (int j = 0; j < 32; ++j) {
        float w = wv[j * 32 + c];
        vn1 = fmaf(sVO[wid][h * 32 + j], w, vn1);
        vn2 = fmaf(sVO[wid][64 + j],     w, vn2);
    }

    if (lane < 32) s_out[(size_t)n * 32 + lane] = act;
    v_out[(size_t)n * 96 + h * 32 + c] = gate * vn1;
    if (h == 0) v_out[(size_t)n * 96 + 64 + c] = gate * vn2;
}

// ---------------------------------------------------------------- output head
__global__ void out_kernel(const float* __restrict__ s,
                           const float* __restrict__ w1,  // [32][16]
                           const float* __restrict__ w2,  // [16][1]
                           float* __restrict__ out) {
    int n = blockIdx.x * blockDim.x + threadIdx.x;
    if (n >= NNODES) return;
    float sv[NC];
    #pragma unroll
    for (int c = 0; c < NC; ++c) sv[c] = s[(size_t)n * NC + c];
    float e = 0.f;
    #pragma unroll
    for (int j = 0; j < 16; ++j) {
        float tj = 0.f;
        #pragma unroll
        for (int c = 0; c < NC; ++c) tj += sv[c] * w1[c * 16 + j];
        e += tj * w2[j];
    }
    out[n] = e;
}

// ---------------------------------------------------------------- launcher
extern "C" void kernel_launch(void* const* d_in, const int* in_sizes, int n_in,
                              void* d_out, int out_size, void* d_ws, size_t ws_size,
                              hipStream_t stream) {
    const float* vectors   = (const float*)d_in[0];
    const int*   specie    = (const int*)  d_in[1];
    const int*   senders   = (const int*)  d_in[2];
    const int*   receivers = (const int*)  d_in[3];
    const float* emb       = (const float*)d_in[4];
    const float* w_rad1    = (const float*)d_in[5];
    const float* w_rad2    = (const float*)d_in[6];
    const float* w_rad_out = (const float*)d_in[7];
    const float* w_lin_s   = (const float*)d_in[8];
    const float* w_lin_v   = (const float*)d_in[9];
    const float* w_sc_s    = (const float*)d_in[10];
    const float* w_sc_v    = (const float*)d_in[11];
    const float* w_out1    = (const float*)d_in[12];
    const float* w_out2    = (const float*)d_in[13];

    char* base = (char*)d_ws;
    size_t off = 0;
    auto alloc = [&](size_t bytes) { char* q = base + off; off += (bytes + 255) & ~(size_t)255; return q; };

    float* nhat4 = (float*)alloc((size_t)NEDGES * 4 * 4);
    float* rb    = (float*)alloc((size_t)NEDGES * 8 * 4);
    float* s_a   = (float*)alloc((size_t)NNODES * NC * 4);
    float* v_a   = (float*)alloc((size_t)NNODES * NC * 3 * 4);
    float* s_b   = (float*)alloc((size_t)NNODES * NC * 4);
    float* v_b   = (float*)alloc((size_t)NNODES * NC * 3 * 4);
    float* aggs  = (float*)alloc((size_t)NNODES * 2 * NC * 4);
    float* aggv  = (float*)alloc((size_t)NNODES * 3 * NC * 3 * 4);  // 34.56 MB; h2p aliases this
    int* deg        = (int*)alloc((size_t)NNODES * 4);
    int* rowstart   = (int*)alloc((size_t)(NNODES + 4) * 4);
    int* cursor     = (int*)alloc((size_t)NNODES * 4);
    int* edge_order = (int*)alloc((size_t)NEDGES * 4);
    // big-path extras
    float*    nh_perm  = (float*)alloc((size_t)NEDGES * 4 * 4);
    int*      snd_perm = (int*)alloc((size_t)NEDGES * 4);
    float*    w1t      = (float*)alloc((size_t)NL * 64 * 8 * 4);
    uint32*   w3p      = (uint32*)alloc((size_t)NL * 160 * 32 * 4);
    _Float16* wgt16    = (_Float16*)alloc((size_t)NEDGES * 160 * 2);
    bool big = (off <= ws_size);

    // h2p aliases aggv: lifetime is within-layer {mlpA, mlpB} which completes
    // before gather_tp writes aggs/aggv. ECHUNK*32*4 = 30.72 MB <= 34.56 MB.
    uint32* h2p = (uint32*)aggv;

    // geometry + CSR (once; graph static across layers)
    geom_kernel<<<(NEDGES + 255) / 256, 256, 0, stream>>>(vectors, nhat4, rb);
    (void)hipMemsetAsync(deg, 0, NNODES * sizeof(int), stream);
    count_kernel<<<(NEDGES + 255) / 256, 256, 0, stream>>>(receivers, deg);
    scan_kernel<<<1, 256, 0, stream>>>(deg, rowstart);
    copy_cursor_kernel<<<(NNODES + 255) / 256, 256, 0, stream>>>(rowstart, cursor);
    fill_kernel<<<(NEDGES + 255) / 256, 256, 0, stream>>>(receivers, cursor, edge_order);
    if (big) {
        perm_kernel<<<(NEDGES + 255) / 256, 256, 0, stream>>>(edge_order, senders, nhat4, nh_perm, snd_perm);
        prepw_kernel<<<(NL * (64 * 8 + 160 * 32) + 255) / 256, 256, 0, stream>>>(w_rad1, w_rad_out, w1t, w3p);
    }

    init_kernel<<<(NNODES * NC + 255) / 256, 256, 0, stream>>>(specie, emb, s_a);
    (void)hipMemsetAsync(v_a, 0, (size_t)NNODES * NC * 3 * sizeof(float), stream);

    float* si = s_a; float* vi = v_a; float* so = s_b; float* vo = v_b;
    for (int l = 0; l < NL; ++l) {
        if (big) {
            for (int ch = 0; ch < 2; ++ch) {
                int iBase = ch * ECHUNK;
                mlpA_kernel<<<(ECHUNK + 255) / 256, 256, 0, stream>>>(
                    rb, edge_order,
                    w1t + (size_t)l * 64 * 8,
                    w_rad2 + (size_t)l * NH * NH,
                    h2p, iBase, ECHUNK);
                mlpB_kernel<<<(ECHUNK + 255) / 256, 256, 0, stream>>>(
                    h2p, w3p + (size_t)l * 160 * 32, wgt16, iBase, ECHUNK);
            }
            gather_tp_kernel<<<NNODES / 8, 512, 0, stream>>>(
                wgt16, nh_perm, snd_perm, rowstart, deg, si, vi, aggs, aggv);
        } else {
            gather_kernel<<<NNODES / 8, 512, 0, stream>>>(
                rb, nhat4, senders, edge_order, rowstart, deg, si, vi,
                w_rad1 + (size_t)l * NBASIS * NH,
                w_rad2 + (size_t)l * NH * NH,
                w_rad_out + (size_t)l * NH * 160,
                aggs, aggv);
        }
        node_kernel<<<(NNODES + 3) / 4, 256, 0, stream>>>(
            specie, aggs, aggv, si, vi,
            w_lin_s + (size_t)l * 64 * 64,
            w_lin_v + (size_t)l * 96 * 32,
            w_sc_s + (size_t)l * NSPEC * NC * 64,
            w_sc_v + (size_t)l * NSPEC * NC * NC,
            so, vo);
        float* ts = si; si = so; so = ts;
        float* tv = vi; vi = vo; vo = tv;
    }

    out_kernel<<<(NNODES + 255) / 256, 256, 0, stream>>>(si, w_out1, w_out2, (float*)d_out);
}

// Round 9
// 1183.081 us; speedup vs baseline: 22.1656x; 1.0800x over previous
//
#include <hip/hip_runtime.h>
#include <math.h>

#define NNODES 30000
#define NEDGES 480000
#define NC 32
#define NL 3
#define NH 64
#define NBASIS 8
#define NSPEC 5
#define INV_AVG 0.0625f   // 1 / AVG_NEIGH
#define ECHUNK 240000     // NEDGES/2 — h2p chunk (aliases aggv); divisible by 64

typedef _Float16 half2v __attribute__((ext_vector_type(2)));
typedef unsigned int uint32;

__device__ __forceinline__ float silu_f(float x) {
    return x / (1.f + __expf(-x));
}
__device__ __forceinline__ float rdlane(float v, int k) {
    return __uint_as_float(__builtin_amdgcn_readlane(__float_as_uint(v), k));
}
__device__ __forceinline__ half2v u2h(uint32 u) {
    union { uint32 u; half2v h; } x; x.u = u; return x.h;
}
__device__ __forceinline__ uint32 packh2(float a, float b) {
    union { uint32 u; half2v h; } x;
    x.h.x = (_Float16)a; x.h.y = (_Float16)b; return x.u;
}

// wgt tile layout: edge gi -> tile T=gi>>6, el=gi&63.
// half h of edge gi lives at  T*10240 + (h>>3)*512 + el*8 + (h&7).

// ---------------------------------------------------------------- geometry
__global__ void geom_kernel(const float* __restrict__ vec,
                            float* __restrict__ nhat4,   // [E][4]
                            float* __restrict__ rb) {    // [E][8]
    int e = blockIdx.x * blockDim.x + threadIdx.x;
    if (e >= NEDGES) return;
    float vx = vec[3*e+0] * 0.25f;   // vectors / R_MAX
    float vy = vec[3*e+1] * 0.25f;
    float vz = vec[3*e+2] * 0.25f;
    float len = sqrtf(vx*vx + vy*vy + vz*vz);      // scaled length
    float inv = 1.f / fmaxf(len, 1e-9f);
    float4 nh = make_float4(vx*inv, vy*inv, vz*inv, 0.f);
    *(float4*)(nhat4 + (size_t)e*4) = nh;
    float x = len * 0.25f;                         // lengths / R_MAX (again)
    float x3 = x*x*x;
    float x6 = x3*x3;
    float x7 = x6*x;
    float x8 = x7*x;
    float env = (x < 1.f) ? (1.f - 28.f*x6 + 48.f*x7 - 21.f*x8) : 0.f;
    float scale = 0.7071067811865476f * inv * env; // sqrt(2/R_MAX)/max(len,eps)*env
    #pragma unroll
    for (int i = 0; i < NBASIS; ++i) {
        rb[NBASIS*e + i] = scale * sinf((float)(i+1) * 3.14159265358979f * x);
    }
}

// ---------------------------------------------------------------- CSR build
__global__ void count_kernel(const int* __restrict__ receivers, int* __restrict__ deg) {
    int e = blockIdx.x * blockDim.x + threadIdx.x;
    if (e >= NEDGES) return;
    atomicAdd(&deg[receivers[e]], 1);
}

__global__ void scan_kernel(const int* __restrict__ deg, int* __restrict__ rowstart) {
    __shared__ int lsum[256];
    __shared__ int loff[256];
    int t = threadIdx.x;
    int lo = t * 118;
    int hi = min(lo + 118, NNODES);
    int s = 0;
    for (int i = lo; i < hi; ++i) s += deg[i];
    lsum[t] = s;
    __syncthreads();
    if (t == 0) {
        int run = 0;
        for (int i = 0; i < 256; ++i) { loff[i] = run; run += lsum[i]; }
    }
    __syncthreads();
    int run = loff[t];
    for (int i = lo; i < hi; ++i) { rowstart[i] = run; run += deg[i]; }
    if (t == 0) rowstart[NNODES] = NEDGES;
}

__global__ void copy_cursor_kernel(const int* __restrict__ rowstart, int* __restrict__ cursor) {
    int i = blockIdx.x * blockDim.x + threadIdx.x;
    if (i < NNODES) cursor[i] = rowstart[i];
}

__global__ void fill_kernel(const int* __restrict__ receivers,
                            int* __restrict__ cursor, int* __restrict__ edge_order) {
    int e = blockIdx.x * blockDim.x + threadIdx.x;
    if (e >= NEDGES) return;
    int pos = atomicAdd(&cursor[receivers[e]], 1);
    edge_order[pos] = e;
}

// ---------------------------------------------------------------- permute edge data (once)
__global__ void perm_kernel(const int* __restrict__ edge_order,
                            const int* __restrict__ senders,
                            const float* __restrict__ nhat4,
                            float* __restrict__ nh_perm, int* __restrict__ snd_perm) {
    int i = blockIdx.x * blockDim.x + threadIdx.x;
    if (i >= NEDGES) return;
    int e = edge_order[i];
    *(float4*)(nh_perm + (size_t)i*4) = *(const float4*)(nhat4 + (size_t)e*4);
    snd_perm[i] = senders[e];
}

// ---------------------------------------------------------------- weight prep (once)
__global__ void prepw_kernel(const float* __restrict__ w1, const float* __restrict__ w3,
                             float* __restrict__ w1t, uint32* __restrict__ w3p) {
    int t = blockIdx.x * blockDim.x + threadIdx.x;
    if (t < NL * 64 * 8) {
        int l = t / 512, r = t % 512, k = r >> 3, b = r & 7;
        w1t[t] = w1[l * 512 + b * 64 + k];
    }
    int u = t - NL * 64 * 8;
    if (u >= 0 && u < NL * 160 * 32) {
        int l = u / 5120, r = u % 5120, o = r >> 5, kp = r & 31;
        const float* wl = w3 + l * 10240;
        w3p[u] = packh2(wl[(2*kp) * 160 + o], wl[(2*kp+1) * 160 + o]);
    }
}

// ---------------------------------------------------------------- node init
__global__ void init_kernel(const int* __restrict__ specie,
                            const float* __restrict__ emb,
                            float* __restrict__ s) {
    int t = blockIdx.x * blockDim.x + threadIdx.x;
    if (t >= NNODES * NC) return;
    int n = t >> 5;
    int c = t & 31;
    s[t] = emb[specie[n] * NC + c];
}

// ---------------------------------------------------------------- MLP stage A
__global__ __launch_bounds__(256, 4) void mlpA_kernel(
    const float* __restrict__ rb,          // [E][8] original order
    const int* __restrict__ edge_order,    // [E]
    const float* __restrict__ w1t,         // [64][8]
    const float* __restrict__ w2,          // [64][64]
    uint32* __restrict__ h2p,              // [ECHUNK][32]
    int iBase, int iCount)
{
    int ii = blockIdx.x * 256 + threadIdx.x;
    if (ii >= iCount) return;
    int e = edge_order[iBase + ii];
    float4 ra = *(const float4*)(rb + (size_t)e * 8);
    float4 rv = *(const float4*)(rb + (size_t)e * 8 + 4);

    float acc[NH];
    #pragma unroll
    for (int j = 0; j < NH; ++j) acc[j] = 0.f;

    #pragma unroll 1
    for (int k = 0; k < NH; ++k) {
        const float* w1k = w1t + k * 8;
        float h;
        h = ra.x * w1k[0];
        h = fmaf(ra.y, w1k[1], h);
        h = fmaf(ra.z, w1k[2], h);
        h = fmaf(ra.w, w1k[3], h);
        h = fmaf(rv.x, w1k[4], h);
        h = fmaf(rv.y, w1k[5], h);
        h = fmaf(rv.z, w1k[6], h);
        h = fmaf(rv.w, w1k[7], h);
        h = silu_f(h);
        const float* w2k = w2 + k * NH;
        #pragma unroll
        for (int j = 0; j < NH; ++j) acc[j] = fmaf(h, w2k[j], acc[j]);
    }

    uint32* op = h2p + (size_t)ii * 32;
    #pragma unroll
    for (int q = 0; q < 8; ++q) {
        uint4 pk;
        pk.x = packh2(silu_f(acc[8*q+0]), silu_f(acc[8*q+1]));
        pk.y = packh2(silu_f(acc[8*q+2]), silu_f(acc[8*q+3]));
        pk.z = packh2(silu_f(acc[8*q+4]), silu_f(acc[8*q+5]));
        pk.w = packh2(silu_f(acc[8*q+6]), silu_f(acc[8*q+7]));
        *(uint4*)(op + 4*q) = pk;
    }
}

// ---------------------------------------------------------------- MLP stage B
// Writes tile-transposed wgt: chunk c of edge (T,el) at T*10240 + c*512 + el*8.
// -> each store instruction covers 64 consecutive 16B = 1KB contiguous.
__global__ __launch_bounds__(256, 8) void mlpB_kernel(
    const uint32* __restrict__ h2p,        // [ECHUNK][32]
    const uint32* __restrict__ w3p,        // [160][32]
    _Float16* __restrict__ wgt16,          // tiled layout
    int iBase, int iCount)
{
    int ii = blockIdx.x * 256 + threadIdx.x;
    if (ii >= iCount) return;

    uint32 h[32];
    const uint32* ip = h2p + (size_t)ii * 32;
    #pragma unroll
    for (int q = 0; q < 8; ++q) {
        uint4 v = *(const uint4*)(ip + 4*q);
        h[4*q+0] = v.x; h[4*q+1] = v.y; h[4*q+2] = v.z; h[4*q+3] = v.w;
    }

    int gi = iBase + ii;
    _Float16* tp = wgt16 + (size_t)(gi >> 6) * 10240 + (gi & 63) * 8;
    #pragma unroll 1
    for (int ob = 0; ob < 160; ob += 8) {
        float t[8];
        #pragma unroll
        for (int o = 0; o < 8; ++o) {
            const uint32* wr = w3p + (ob + o) * 32;
            float a = 0.f;
            #pragma unroll
            for (int kp = 0; kp < 32; ++kp)
                a = __builtin_amdgcn_fdot2(u2h(h[kp]), u2h(wr[kp]), a, false);
            t[o] = a;
        }
        uint4 pk;
        pk.x = packh2(t[0], t[1]);
        pk.y = packh2(t[2], t[3]);
        pk.z = packh2(t[4], t[5]);
        pk.w = packh2(t[6], t[7]);
        *(uint4*)(tp + (ob >> 3) * 512) = pk;
    }
}

// ---------------------------------------------------------------- gather + TP
__global__ __launch_bounds__(512) void gather_tp_kernel(
    const _Float16* __restrict__ wgt16,   // tiled layout
    const float* __restrict__ nh_perm,    // [E][4]
    const int* __restrict__ snd_perm,     // [E]
    const int* __restrict__ rowstart, const int* __restrict__ deg,
    const float* __restrict__ s_in, const float* __restrict__ v_in,  // v: [N][3][32]
    float* __restrict__ agg_s,      // [N][64]
    float* __restrict__ agg_v)      // [N][96][3]
{
    int lane = threadIdx.x & 63;
    int wid  = threadIdx.x >> 6;
    int n = blockIdx.x * 8 + wid;
    if (n >= NNODES) return;

    int c = lane & 31;
    int half = lane >> 5;
    int off01 = half * 32 + c;

    // tile-layout offsets for this lane (within a tile, before el*8 shift)
    int o0 = ((off01 >> 3) << 9) + (off01 & 7);            // half index off01
    int o2 = (((128 + c) >> 3) << 9) + (c & 7);            // half index 128+c

    float accS = 0.f;
    float aVa0 = 0.f, aVa1 = 0.f, aVa2 = 0.f;   // half0: path2, half1: path3
    float aVb0 = 0.f, aVb1 = 0.f, aVb2 = 0.f;   // half0: path4, half1: garbage

    int start = rowstart[n];
    int cnt   = deg[n];

    for (int i = 0; i < cnt; ++i) {
        int idx = start + i;
        float4 nh = *(const float4*)(nh_perm + (size_t)idx * 4);
        int snd = snd_perm[idx];
        const _Float16* tp = wgt16 + (size_t)(idx >> 6) * 10240 + (idx & 63) * 8;

        float d0  = (float)tp[o0];           // half0: wgt0[c]  half1: wgt1[c]
        float d1  = (float)tp[o0 + 4096];    // half0: wgt2[c]  half1: wgt3[c]
        float d2f = (float)tp[o2];           // wgt4[c] (half1 discards)

        float su = s_in[(size_t)snd * NC + c];
        float v0 = v_in[(size_t)snd * 96 + c];
        float v1 = v_in[(size_t)snd * 96 + 32 + c];
        float v2 = v_in[(size_t)snd * 96 + 64 + c];
        float ndv = nh.x * v0;
        ndv = fmaf(nh.y, v1, ndv);
        ndv = fmaf(nh.z, v2, ndv);

        float sSel = half ? ndv : su;          // path1 vs path0 multiplier
        accS = fmaf(d0, sSel, accS);
        float scale = half ? d1 : d1 * su;     // path3: w3 ; path2: w2*su
        float f0 = half ? v0 : nh.x;
        float f1 = half ? v1 : nh.y;
        float f2 = half ? v2 : nh.z;
        aVa0 = fmaf(scale, f0, aVa0);
        aVa1 = fmaf(scale, f1, aVa1);
        aVa2 = fmaf(scale, f2, aVa2);
        float m4 = half ? 0.f : d2f;           // path4 only on half0
        aVb0 = fmaf(m4, fmaf(nh.x, ndv, -v0 * (1.f / 3.f)), aVb0);
        aVb1 = fmaf(m4, fmaf(nh.y, ndv, -v1 * (1.f / 3.f)), aVb1);
        aVb2 = fmaf(m4, fmaf(nh.z, ndv, -v2 * (1.f / 3.f)), aVb2);
    }

    agg_s[(size_t)n * 64 + lane] = accS;
    float* av = agg_v + (size_t)n * 288;
    if (half == 0) {
        av[c * 3 + 0] = aVa0; av[c * 3 + 1] = aVa1; av[c * 3 + 2] = aVa2;                      // path2
        av[(64 + c) * 3 + 0] = aVb0; av[(64 + c) * 3 + 1] = aVb1; av[(64 + c) * 3 + 2] = aVb2; // path4
    } else {
        av[(32 + c) * 3 + 0] = aVa0; av[(32 + c) * 3 + 1] = aVa1; av[(32 + c) * 3 + 2] = aVa2; // path3
    }
}

// ---------------------------------------------------------------- fallback gather (Round-2)
__global__ __launch_bounds__(512) void gather_kernel(
    const float* __restrict__ rb, const float* __restrict__ nhat4,
    const int* __restrict__ senders, const int* __restrict__ edge_order,
    const int* __restrict__ rowstart, const int* __restrict__ deg,
    const float* __restrict__ s_in, const float* __restrict__ v_in,
    const float* __restrict__ w1, const float* __restrict__ w2, const float* __restrict__ w3,
    float* __restrict__ agg_s, float* __restrict__ agg_v)
{
    __shared__ float sW2[NH * NH];
    __shared__ float sW3[NH * 160];
    for (int i = threadIdx.x; i < NH * NH;  i += 512) sW2[i] = w2[i];
    for (int i = threadIdx.x; i < NH * 160; i += 512) sW3[i] = w3[i];
    __syncthreads();
    int lane = threadIdx.x & 63;
    int wid  = threadIdx.x >> 6;
    int n = blockIdx.x * 8 + wid;
    if (n >= NNODES) return;
    int c = lane & 31;
    int half = lane >> 5;
    float w1r[8];
    #pragma unroll
    for (int b = 0; b < 8; ++b) w1r[b] = w1[b * NH + lane];
    float accS = 0.f;
    float aVa0 = 0.f, aVa1 = 0.f, aVa2 = 0.f;
    float aVb0 = 0.f, aVb1 = 0.f, aVb2 = 0.f;
    int start = rowstart[n];
    int cnt   = deg[n];
    for (int i = 0; i < cnt; ++i) {
        int e   = edge_order[start + i];
        int snd = senders[e];
        float4 nh  = *(const float4*)(nhat4 + (size_t)e * 4);
        float4 rba = *(const float4*)(rb + (size_t)e * 8);
        float4 rbb = *(const float4*)(rb + (size_t)e * 8 + 4);
        float h1v;
        h1v = rba.x * w1r[0];
        h1v = fmaf(rba.y, w1r[1], h1v);
        h1v = fmaf(rba.z, w1r[2], h1v);
        h1v = fmaf(rba.w, w1r[3], h1v);
        h1v = fmaf(rbb.x, w1r[4], h1v);
        h1v = fmaf(rbb.y, w1r[5], h1v);
        h1v = fmaf(rbb.z, w1r[6], h1v);
        h1v = fmaf(rbb.w, w1r[7], h1v);
        h1v = silu_f(h1v);
        float a0 = 0.f, a1 = 0.f;
        #pragma unroll
        for (int k = 0; k < NH; k += 2) {
            a0 = fmaf(rdlane(h1v, k),     sW2[k * NH + lane],       a0);
            a1 = fmaf(rdlane(h1v, k + 1), sW2[(k + 1) * NH + lane], a1);
        }
        float h2v = silu_f(a0 + a1);
        float d0a = 0.f, d0b = 0.f, d1a = 0.f, d1b = 0.f, d2a = 0.f, d2b = 0.f;
        #pragma unroll
        for (int k = 0; k < NH; k += 2) {
            float hA = rdlane(h2v, k);
            float hB = rdlane(h2v, k + 1);
            d0a = fmaf(hA, sW3[k * 160 + lane],            d0a);
            d1a = fmaf(hA, sW3[k * 160 + 64 + lane],       d1a);
            d2a = fmaf(hA, sW3[k * 160 + 128 + c],         d2a);
            d0b = fmaf(hB, sW3[(k + 1) * 160 + lane],      d0b);
            d1b = fmaf(hB, sW3[(k + 1) * 160 + 64 + lane], d1b);
            d2b = fmaf(hB, sW3[(k + 1) * 160 + 128 + c],   d2b);
        }
        float d0 = d0a + d0b;
        float d1 = d1a + d1b;
        float d2 = d2a + d2b;
        float su = s_in[(size_t)snd * NC + c];
        float v0 = v_in[(size_t)snd * 96 + c];
        float v1 = v_in[(size_t)snd * 96 + 32 + c];
        float v2 = v_in[(size_t)snd * 96 + 64 + c];
        float ndv = nh.x * v0;
        ndv = fmaf(nh.y, v1, ndv);
        ndv = fmaf(nh.z, v2, ndv);
        float sSel = half ? ndv : su;
        accS = fmaf(d0, sSel, accS);
        float scale = half ? d1 : d1 * su;
        float f0 = half ? v0 : nh.x;
        float f1 = half ? v1 : nh.y;
        float f2 = half ? v2 : nh.z;
        aVa0 = fmaf(scale, f0, aVa0);
        aVa1 = fmaf(scale, f1, aVa1);
        aVa2 = fmaf(scale, f2, aVa2);
        float m4 = half ? 0.f : d2;
        aVb0 = fmaf(m4, fmaf(nh.x, ndv, -v0 * (1.f / 3.f)), aVb0);
        aVb1 = fmaf(m4, fmaf(nh.y, ndv, -v1 * (1.f / 3.f)), aVb1);
        aVb2 = fmaf(m4, fmaf(nh.z, ndv, -v2 * (1.f / 3.f)), aVb2);
    }
    agg_s[(size_t)n * 64 + lane] = accS;
    float* av = agg_v + (size_t)n * 288;
    if (half == 0) {
        av[c * 3 + 0] = aVa0; av[c * 3 + 1] = aVa1; av[c * 3 + 2] = aVa2;
        av[(64 + c) * 3 + 0] = aVb0; av[(64 + c) * 3 + 1] = aVb1; av[(64 + c) * 3 + 2] = aVb2;
    } else {
        av[(32 + c) * 3 + 0] = aVa0; av[(32 + c) * 3 + 1] = aVa1; av[(32 + c) * 3 + 2] = aVa2;
    }
}

// ---------------------------------------------------------------- node update (v2)
__global__ __launch_bounds__(256) void node_kernel(
    const int* __restrict__ specie,
    const float* __restrict__ agg_s, const float* __restrict__ agg_v,
    const float* __restrict__ s_in,  const float* __restrict__ v_in,
    const float* __restrict__ wls,   // [64][64]
    const float* __restrict__ wlv,   // [96][32]
    const float* __restrict__ wscs,  // [5][32][64]
    const float* __restrict__ wscv,  // [5][32][32]
    float* __restrict__ s_out, float* __restrict__ v_out)
{
    __shared__ float sAV[4][288];
    __shared__ float sVO[4][96];

    int lane = threadIdx.x & 63;
    int wid  = threadIdx.x >> 6;
    int n = blockIdx.x * 4 + wid;
    if (n >= NNODES) return;
    int sp = specie[n];

    const float* av = agg_v + (size_t)n * 288;
    sAV[wid][lane]       = av[lane];
    sAV[wid][64 + lane]  = av[64 + lane];
    sAV[wid][128 + lane] = av[128 + lane];
    sAV[wid][192 + lane] = av[192 + lane];
    if (lane < 32) sAV[wid][256 + lane] = av[256 + lane];
    const float* vo = v_in + (size_t)n * 96;
    if (lane < 32) {
        sVO[wid][lane]      = vo[lane];
        sVO[wid][32 + lane] = vo[32 + lane];
        sVO[wid][64 + lane] = vo[64 + lane];
    }

    float asv = agg_s[(size_t)n * 64 + lane];
    float sv  = s_in[(size_t)n * 32 + (lane & 31)];

    __syncthreads();

    float sg = 0.f;
    #pragma unroll
    for (int j = 0; j < 64; ++j)
        sg = fmaf(rdlane(asv, j), wls[j * 64 + lane], sg);
    sg *= INV_AVG;
    const float* ws = wscs + (size_t)sp * 32 * 64;
    #pragma unroll
    for (int j = 0; j < 32; ++j)
        sg = fmaf(rdlane(sv, j), ws[j * 64 + lane], sg);
    float act  = silu_f(sg);
    float gate = __shfl(act, (lane & 31) + 32);

    int c = lane & 31;
    int h = lane >> 5;
    float vn1 = 0.f, vn2 = 0.f;
    #pragma unroll
    for (int p = 0; p < 96; ++p) {
        float w = wlv[p * 32 + c];
        vn1 = fmaf(sAV[wid][3 * p + h], w, vn1);
        vn2 = fmaf(sAV[wid][3 * p + 2], w, vn2);
    }
    vn1 *= INV_AVG; vn2 *= INV_AVG;
    const float* wv = wscv + (size_t)sp * 32 * 32;
    #pragma unroll
    for (int j = 0; j < 32; ++j) {
        float w = wv[j * 32 + c];
        vn1 = fmaf(sVO[wid][h * 32 + j], w, vn1);
        vn2 = fmaf(sVO[wid][64 + j],     w, vn2);
    }

    if (lane < 32) s_out[(size_t)n * 32 + lane] = act;
    v_out[(size_t)n * 96 + h * 32 + c] = gate * vn1;
    if (h == 0) v_out[(size_t)n * 96 + 64 + c] = gate * vn2;
}

// ---------------------------------------------------------------- output head
__global__ void out_kernel(const float* __restrict__ s,
                           const float* __restrict__ w1,  // [32][16]
                           const float* __restrict__ w2,  // [16][1]
                           float* __restrict__ out) {
    int n = blockIdx.x * blockDim.x + threadIdx.x;
    if (n >= NNODES) return;
    float sv[NC];
    #pragma unroll
    for (int c = 0; c < NC; ++c) sv[c] = s[(size_t)n * NC + c];
    float e = 0.f;
    #pragma unroll
    for (int j = 0; j < 16; ++j) {
        float tj = 0.f;
        #pragma unroll
        for (int c = 0; c < NC; ++c) tj += sv[c] * w1[c * 16 + j];
        e += tj * w2[j];
    }
    out[n] = e;
}

// ---------------------------------------------------------------- launcher
extern "C" void kernel_launch(void* const* d_in, const int* in_sizes, int n_in,
                              void* d_out, int out_size, void* d_ws, size_t ws_size,
                              hipStream_t stream) {
    const float* vectors   = (const float*)d_in[0];
    const int*   specie    = (const int*)  d_in[1];
    const int*   senders   = (const int*)  d_in[2];
    const int*   receivers = (const int*)  d_in[3];
    const float* emb       = (const float*)d_in[4];
    const float* w_rad1    = (const float*)d_in[5];
    const float* w_rad2    = (const float*)d_in[6];
    const float* w_rad_out = (const float*)d_in[7];
    const float* w_lin_s   = (const float*)d_in[8];
    const float* w_lin_v   = (const float*)d_in[9];
    const float* w_sc_s    = (const float*)d_in[10];
    const float* w_sc_v    = (const float*)d_in[11];
    const float* w_out1    = (const float*)d_in[12];
    const float* w_out2    = (const float*)d_in[13];

    char* base = (char*)d_ws;
    size_t off = 0;
    auto alloc = [&](size_t bytes) { char* q = base + off; off += (bytes + 255) & ~(size_t)255; return q; };

    float* nhat4 = (float*)alloc((size_t)NEDGES * 4 * 4);
    float* rb    = (float*)alloc((size_t)NEDGES * 8 * 4);
    float* s_a   = (float*)alloc((size_t)NNODES * NC * 4);
    float* v_a   = (float*)alloc((size_t)NNODES * NC * 3 * 4);
    float* s_b   = (float*)alloc((size_t)NNODES * NC * 4);
    float* v_b   = (float*)alloc((size_t)NNODES * NC * 3 * 4);
    float* aggs  = (float*)alloc((size_t)NNODES * 2 * NC * 4);
    float* aggv  = (float*)alloc((size_t)NNODES * 3 * NC * 3 * 4);  // 34.56 MB; h2p aliases this
    int* deg        = (int*)alloc((size_t)NNODES * 4);
    int* rowstart   = (int*)alloc((size_t)(NNODES + 4) * 4);
    int* cursor     = (int*)alloc((size_t)NNODES * 4);
    int* edge_order = (int*)alloc((size_t)NEDGES * 4);
    // big-path extras
    float*    nh_perm  = (float*)alloc((size_t)NEDGES * 4 * 4);
    int*      snd_perm = (int*)alloc((size_t)NEDGES * 4);
    float*    w1t      = (float*)alloc((size_t)NL * 64 * 8 * 4);
    uint32*   w3p      = (uint32*)alloc((size_t)NL * 160 * 32 * 4);
    _Float16* wgt16    = (_Float16*)alloc((size_t)NEDGES * 160 * 2);
    bool big = (off <= ws_size);

    uint32* h2p = (uint32*)aggv;   // aliased; disjoint lifetime within layer

    geom_kernel<<<(NEDGES + 255) / 256, 256, 0, stream>>>(vectors, nhat4, rb);
    (void)hipMemsetAsync(deg, 0, NNODES * sizeof(int), stream);
    count_kernel<<<(NEDGES + 255) / 256, 256, 0, stream>>>(receivers, deg);
    scan_kernel<<<1, 256, 0, stream>>>(deg, rowstart);
    copy_cursor_kernel<<<(NNODES + 255) / 256, 256, 0, stream>>>(rowstart, cursor);
    fill_kernel<<<(NEDGES + 255) / 256, 256, 0, stream>>>(receivers, cursor, edge_order);
    if (big) {
        perm_kernel<<<(NEDGES + 255) / 256, 256, 0, stream>>>(edge_order, senders, nhat4, nh_perm, snd_perm);
        prepw_kernel<<<(NL * (64 * 8 + 160 * 32) + 255) / 256, 256, 0, stream>>>(w_rad1, w_rad_out, w1t, w3p);
    }

    init_kernel<<<(NNODES * NC + 255) / 256, 256, 0, stream>>>(specie, emb, s_a);
    (void)hipMemsetAsync(v_a, 0, (size_t)NNODES * NC * 3 * sizeof(float), stream);

    float* si = s_a; float* vi = v_a; float* so = s_b; float* vo = v_b;
    for (int l = 0; l < NL; ++l) {
        if (big) {
            for (int ch = 0; ch < 2; ++ch) {
                int iBase = ch * ECHUNK;
                mlpA_kernel<<<(ECHUNK + 255) / 256, 256, 0, stream>>>(
                    rb, edge_order,
                    w1t + (size_t)l * 64 * 8,
                    w_rad2 + (size_t)l * NH * NH,
                    h2p, iBase, ECHUNK);
                mlpB_kernel<<<(ECHUNK + 255) / 256, 256, 0, stream>>>(
                    h2p, w3p + (size_t)l * 160 * 32, wgt16, iBase, ECHUNK);
            }
            gather_tp_kernel<<<NNODES / 8, 512, 0, stream>>>(
                wgt16, nh_perm, snd_perm, rowstart, deg, si, vi, aggs, aggv);
        } else {
            gather_kernel<<<NNODES / 8, 512, 0, stream>>>(
                rb, nhat4, senders, edge_order, rowstart, deg, si, vi,
                w_rad1 + (size_t)l * NBASIS * NH,
                w_rad2 + (size_t)l * NH * NH,
                w_rad_out + (size_t)l * NH * 160,
                aggs, aggv);
        }
        node_kernel<<<(NNODES + 3) / 4, 256, 0, stream>>>(
            specie, aggs, aggv, si, vi,
            w_lin_s + (size_t)l * 64 * 64,
            w_lin_v + (size_t)l * 96 * 32,
            w_sc_s + (size_t)l * NSPEC * NC * 64,
            w_sc_v + (size_t)l * NSPEC * NC * NC,
            so, vo);
        float* ts = si; si = so; so = ts;
        float* tv = vi; vi = vo; vo = tv;
    }

    out_kernel<<<(NNODES + 255) / 256, 256, 0, stream>>>(si, w_out1, w_out2, (float*)d_out);
}